// Round 10
// baseline (258.545 us; speedup 1.0000x reference)
//
#include <hip/hip_runtime.h>
#include <math.h>

#define OUTC 304
#define NBK  784         // max 64-atom bins (>= ceil(50000/64)=782)
#define CAP  3072        // payload slots per bin (lambda ~2558 at 2M items)
#define SC_K 11          // LDS staging depth per bucket (73.5 KB total -> 2 blocks/CU)
#define SC_F 8           // flush every SC_F iterations (lambda ~5.2/bucket)
#define OVF_CAP 65536

// ---------------- fused prep: zero counters + ecfp copy + angular edge records ----------------
__global__ __launch_bounds__(256) void k_prep(const float* __restrict__ angd,
                                              const float* __restrict__ angsw,
                                              const int* __restrict__ aedst,
                                              const int* __restrict__ species,
                                              unsigned* __restrict__ erec, int e_ang,
                                              const float* __restrict__ ecfp,
                                              float* __restrict__ out, int total4,
                                              int* __restrict__ gcnt, int nz) {
    int i = blockIdx.x * 256 + threadIdx.x;
    if (i < nz) gcnt[i] = 0;
    if (i < total4) {
        int row = i >> 2, c4 = i & 3;
        ((float4*)out)[row * (OUTC / 4) + c4] = ((const float4*)ecfp)[i];
    }
    if (i < e_ang) {
        int z = species[aedst[i]];
        unsigned sp = (z == 6) ? 1u : (z == 7) ? 2u : (z == 8) ? 3u : 0u;
        float d = angd[i], s = angsw[i];
        unsigned dq = (unsigned)fminf(fmaxf((d - 0.8f) * (4095.0f / 2.7f) + 0.5f, 0.f), 4095.f);
        unsigned sq = (unsigned)fminf(fmaxf(s * 16383.0f + 0.5f, 0.f), 16383.f);
        erec[i] = dq | (sq << 12) | (sp << 26);
    }
}

// ============ LDS-staged counting scatter (radial), 64-atom buckets ============
// payload: x = dq16|sq16 ; y = loc6 | sp2<<6 | bb1<<8
// lcnt doubles as lbase after the scan (saves 3KB LDS -> 2 blocks/CU)
__global__ __launch_bounds__(512) void k_scatter_rad(
        const float* __restrict__ dist, const float* __restrict__ sw,
        const int* __restrict__ bond_order, const int* __restrict__ esrc,
        const int* __restrict__ edst, const int* __restrict__ species,
        int* __restrict__ gcnt, uint2* __restrict__ payload,
        uint4* __restrict__ ovf, int* __restrict__ ovfc,
        int n, int span, int nb) {
    __shared__ unsigned stgx[NBK * SC_K], stgy[NBK * SC_K];
    __shared__ int lcnt[NBK];
    __shared__ int pre[NBK + 2];
    __shared__ int wsum[8];
    const int tid = threadIdx.x;
    for (int i = tid; i < nb; i += 512) lcnt[i] = 0;
    __syncthreads();
    int base = blockIdx.x * span, end = min(base + span, n);
    if (base >= end) return;
    int pend = 0;
    for (int i0 = base; i0 < end; i0 += 512) {
        int e = i0 + tid;
        if (e < end) {
            float d = dist[e];
            float s = sw[e];
            int bo = bond_order[e];
            unsigned bb = (bo == 3 || bo == 5) ? 1u : 0u;
            int z = species[edst[e]];
            unsigned sp = (z == 6) ? 1u : (z == 7) ? 2u : (z == 8) ? 3u : 0u;
            int c = esrc[e];
            unsigned dq = (unsigned)fminf(fmaxf((d - 0.8f) * (65535.0f / 4.4f) + 0.5f, 0.f), 65535.f);
            unsigned sq = (unsigned)fminf(fmaxf(s * 65535.0f + 0.5f, 0.f), 65535.f);
            unsigned px = dq | (sq << 16);
            unsigned py = (unsigned)(c & 63) | (sp << 6) | (bb << 8);
            int b = c >> 6;
            int slot = atomicAdd(&lcnt[b], 1);
            if (slot < SC_K) { stgx[b * SC_K + slot] = px; stgy[b * SC_K + slot] = py; }
            else { int oi = atomicAdd(ovfc, 1); if (oi < OVF_CAP) ovf[oi] = make_uint4(px, py, (unsigned)c, 0u); }
        }
        if (++pend == SC_F || i0 + 512 >= end) {
            pend = 0;
            __syncthreads();
            int lane = tid & 63, wid = tid >> 6;
            int b0 = 2 * tid, b1 = 2 * tid + 1;
            int ca = (b0 < nb) ? min(lcnt[b0], SC_K) : 0;
            int cb = (b1 < nb) ? min(lcnt[b1], SC_K) : 0;
            int s2 = ca + cb, inc = s2;
#pragma unroll
            for (int dd = 1; dd < 64; dd <<= 1) {
                int u = __shfl_up(inc, dd);
                if (lane >= dd) inc += u;
            }
            if (lane == 63) wsum[wid] = inc;
            __syncthreads();
            int wbase = 0;
#pragma unroll
            for (int w = 0; w < 8; ++w) if (w < wid) wbase += wsum[w];
            int excl = wbase + inc - s2;
            if (b0 <= nb) pre[b0] = excl;
            if (b1 <= nb) pre[b1] = excl + ca;
            // reuse lcnt as lbase (each thread owns entries b0,b1)
            if (b0 < nb && ca > 0) lcnt[b0] = atomicAdd(&gcnt[b0], ca);
            if (b1 < nb && cb > 0) lcnt[b1] = atomicAdd(&gcnt[b1], cb);
            __syncthreads();
            int T = pre[nb];
            for (int t2 = tid; t2 < T; t2 += 512) {
                int lo = 0, hi = nb;
                while (hi - lo > 1) { int mid = (lo + hi) >> 1; if (pre[mid] <= t2) lo = mid; else hi = mid; }
                int b = lo, k = t2 - pre[b];
                unsigned px = stgx[b * SC_K + k], py = stgy[b * SC_K + k];
                int gpos = lcnt[b] + k;
                if (gpos < CAP) payload[(size_t)b * CAP + gpos] = make_uint2(px, py);
                else { int oi = atomicAdd(ovfc, 1); if (oi < OVF_CAP) ovf[oi] = make_uint4(px, py, (unsigned)(b * 64 + (py & 63u)), 0u); }
            }
            __syncthreads();
            for (int i = tid; i < nb; i += 512) lcnt[i] = 0;
            __syncthreads();
        }
    }
}

// ============ LDS-staged counting scatter (angular), 64-atom buckets ============
// payload: x = tq16|dq16 ; y = sq16 | loc6<<16 | pair4<<22
__global__ __launch_bounds__(512) void k_scatter_ang(
        const float* __restrict__ angles, const unsigned* __restrict__ erec,
        const int* __restrict__ central, const int* __restrict__ psrc,
        const int* __restrict__ pdst,
        int* __restrict__ gcnt, uint2* __restrict__ payload,
        uint4* __restrict__ ovf, int* __restrict__ ovfc,
        int n, int span, int nb) {
    __shared__ unsigned stgx[NBK * SC_K], stgy[NBK * SC_K];
    __shared__ int lcnt[NBK];
    __shared__ int pre[NBK + 2];
    __shared__ int wsum[8];
    const int tid = threadIdx.x;
    for (int i = tid; i < nb; i += 512) lcnt[i] = 0;
    __syncthreads();
    int base = blockIdx.x * span, end = min(base + span, n);
    if (base >= end) return;
    int pend = 0;
    for (int i0 = base; i0 < end; i0 += 512) {
        int p = i0 + tid;
        if (p < end) {
            unsigned rs = erec[psrc[p]];
            unsigned rt = erec[pdst[p]];
            float dsrc = 0.8f + (float)(rs & 0xfffu) * (2.7f / 4095.0f);
            float dtgt = 0.8f + (float)(rt & 0xfffu) * (2.7f / 4095.0f);
            float ss = (float)((rs >> 12) & 0x3fffu) * (1.0f / 16383.0f);
            float st = (float)((rt >> 12) & 0x3fffu) * (1.0f / 16383.0f);
            int sps = (int)(rs >> 26), spt = (int)(rt >> 26);
            int i = min(sps, spt), j = max(sps, spt);
            unsigned pair = (unsigned)(i * 4 - (i * (i - 1)) / 2 + (j - i));
            float d12 = 0.5f * (dsrc + dtgt);
            float scale = 2.0f * ss * st;
            float th = angles[p];
            int c = central[p];
            unsigned tq = (unsigned)fminf(fmaxf(th * (65535.0f / 3.14159265358979f) + 0.5f, 0.f), 65535.f);
            unsigned dq = (unsigned)fminf(fmaxf((d12 - 0.8f) * (65535.0f / 2.7f) + 0.5f, 0.f), 65535.f);
            unsigned sq = (unsigned)fminf(fmaxf(scale * (65535.0f / 2.0f) + 0.5f, 0.f), 65535.f);
            unsigned px = tq | (dq << 16);
            unsigned py = sq | ((unsigned)(c & 63) << 16) | (pair << 22);
            int b = c >> 6;
            int slot = atomicAdd(&lcnt[b], 1);
            if (slot < SC_K) { stgx[b * SC_K + slot] = px; stgy[b * SC_K + slot] = py; }
            else { int oi = atomicAdd(ovfc, 1); if (oi < OVF_CAP) ovf[oi] = make_uint4(px, py, (unsigned)c, 1u); }
        }
        if (++pend == SC_F || i0 + 512 >= end) {
            pend = 0;
            __syncthreads();
            int lane = tid & 63, wid = tid >> 6;
            int b0 = 2 * tid, b1 = 2 * tid + 1;
            int ca = (b0 < nb) ? min(lcnt[b0], SC_K) : 0;
            int cb = (b1 < nb) ? min(lcnt[b1], SC_K) : 0;
            int s2 = ca + cb, inc = s2;
#pragma unroll
            for (int dd = 1; dd < 64; dd <<= 1) {
                int u = __shfl_up(inc, dd);
                if (lane >= dd) inc += u;
            }
            if (lane == 63) wsum[wid] = inc;
            __syncthreads();
            int wbase = 0;
#pragma unroll
            for (int w = 0; w < 8; ++w) if (w < wid) wbase += wsum[w];
            int excl = wbase + inc - s2;
            if (b0 <= nb) pre[b0] = excl;
            if (b1 <= nb) pre[b1] = excl + ca;
            if (b0 < nb && ca > 0) lcnt[b0] = atomicAdd(&gcnt[b0], ca);
            if (b1 < nb && cb > 0) lcnt[b1] = atomicAdd(&gcnt[b1], cb);
            __syncthreads();
            int T = pre[nb];
            for (int t2 = tid; t2 < T; t2 += 512) {
                int lo = 0, hi = nb;
                while (hi - lo > 1) { int mid = (lo + hi) >> 1; if (pre[mid] <= t2) lo = mid; else hi = mid; }
                int b = lo, k = t2 - pre[b];
                unsigned px = stgx[b * SC_K + k], py = stgy[b * SC_K + k];
                int gpos = lcnt[b] + k;
                if (gpos < CAP) payload[(size_t)b * CAP + gpos] = make_uint2(px, py);
                else { int oi = atomicAdd(ovfc, 1); if (oi < OVF_CAP) ovf[oi] = make_uint4(px, py, (unsigned)(b * 64 + ((py >> 16) & 63u)), 1u); }
            }
            __syncthreads();
            for (int i = tid; i < nb; i += 512) lcnt[i] = 0;
            __syncthreads();
        }
    }
}

// ---------------- per-item accumulate helpers: window + per-lane threshold ----------------
// Cost model (r8 lesson): time ~ active-lane ds_atomic ops. Window trims issues
// and decode; threshold masks lanes so only significant values hit the LDS pipe.
#define VTHR 1.5e-3f

__device__ __forceinline__ void proc_rad(uint2 pl, float* acc) {
    float d = 0.8f + (float)(pl.x & 0xffffu) * (4.4f / 65535.0f);
    float coef = 0.25f * (float)(pl.x >> 16) * (1.0f / 65535.0f);
    int bidx = (int)(pl.y & 63u) * 129 + (int)((pl.y >> 6) & 3u) * 32 + (int)((pl.y >> 8) & 1u);
    int c0 = (int)((d - 0.8f) * (1.0f / 0.275f)) - 1;
    c0 = max(0, min(12, c0));
    float dd = d - (0.8f + 0.275f * (float)c0);
    float* ap = acc + bidx + c0 * 2;
#pragma unroll
    for (int kk = 0; kk < 4; ++kk) {
        float delta = dd - 0.275f * (float)kk;
        float v = coef * __expf(-16.0f * delta * delta);
        if (v > VTHR) atomicAdd(&ap[kk * 2], v);
    }
}

__device__ __forceinline__ void proc_ang(uint2 pl, float* acc) {
    float th    = (float)(pl.x & 0xffffu) * (3.14159265358979f / 65535.0f);
    float d12   = 0.8f + (float)(pl.x >> 16) * (2.7f / 65535.0f);
    float scale = (float)(pl.y & 0xffffu) * (2.0f / 65535.0f);
    int rowb = (int)((pl.y >> 16) & 63u) * 161 + (int)((pl.y >> 22) & 15u) * 16;
    int z0 = (int)(th * (4.0f / 3.14159265358979f) - 0.5f);
    z0 = max(0, min(2, z0));
    float cz = (z0 == 0) ? 0.92387953251f : ((z0 == 1) ? 0.38268343236f : -0.38268343236f);
    float sz = (z0 == 0) ? 0.38268343236f : 0.92387953251f;
    float sth, cth;
    __sincosf(th, &sth, &cth);
    float cq = cth * cz + sth * sz;
    float sq = sth * cz - cth * sz;
    float xa = 0.5f + 0.5f * cq;
    float cq1 = 0.70710678119f * (cq + sq);
    float xb = 0.5f + 0.5f * cq1;
    float x2, x4, x8, x16, f1a, f1b;
    x2 = xa * xa; x4 = x2 * x2; x8 = x4 * x4; x16 = x8 * x8; f1a = x16 * x16;
    x2 = xb * xb; x4 = x2 * x2; x8 = x4 * x4; x16 = x8 * x8; f1b = x16 * x16;
    int ar = (int)((d12 - 0.8f) * (1.0f / 0.675f) + 0.5f);
    int a0 = max(0, min(1, ar - 1));
    float da = d12 - (0.8f + 0.675f * (float)a0);
    float* ap = acc + rowb + a0 * 4 + z0;
#pragma unroll
    for (int aa = 0; aa < 3; ++aa) {
        float delta = da - 0.675f * (float)aa;
        float f2 = __expf(-8.0f * delta * delta) * scale;
        float v0 = f2 * f1a;
        float v1 = f2 * f1b;
        if (v0 > VTHR) atomicAdd(&ap[aa * 4], v0);
        if (v1 > VTHR) atomicAdd(&ap[aa * 4 + 1], v1);
    }
}

// ---------------- radial accumulate: one 64-atom bin per block ----------------
__global__ __launch_bounds__(512) void k_accum_rad(const uint2* __restrict__ payload,
                                                   const int* __restrict__ gcnt,
                                                   float* __restrict__ out, int n_atoms) {
    __shared__ float acc[64 * 129];   // 33 KB, padded stride
    int b = blockIdx.x;
    for (int i = threadIdx.x; i < 64 * 129; i += 512) acc[i] = 0.f;
    __syncthreads();
    int len = min(gcnt[b], CAP);
    const uint2* pp = payload + (size_t)b * CAP;
    for (int r = threadIdx.x; r < len; r += 512) proc_rad(pp[r], acc);
    __syncthreads();
    int a0 = b * 64;
    for (int i = threadIdx.x; i < 64 * 128; i += 512) {
        int la = i >> 7, cc = i & 127;
        int atom = a0 + la;
        if (atom < n_atoms) out[(size_t)atom * OUTC + 16 + cc] = acc[la * 129 + cc];
    }
}

// ---------------- angular accumulate: one 64-atom bin per block ----------------
__global__ __launch_bounds__(512) void k_accum_ang(const uint2* __restrict__ payload,
                                                   const int* __restrict__ gcnt,
                                                   float* __restrict__ out, int n_atoms) {
    __shared__ float acc[64 * 161];   // 41 KB, padded stride
    int b = blockIdx.x;
    for (int i = threadIdx.x; i < 64 * 161; i += 512) acc[i] = 0.f;
    __syncthreads();
    int len = min(gcnt[b], CAP);
    const uint2* pp = payload + (size_t)b * CAP;
    for (int r = threadIdx.x; r < len; r += 512) proc_ang(pp[r], acc);
    __syncthreads();
    int a0 = b * 64;
    for (int i = threadIdx.x; i < 64 * 160; i += 512) {
        int la = i / 160, cc = i - la * 160;
        int atom = a0 + la;
        if (atom < n_atoms) out[(size_t)atom * OUTC + 144 + cc] = acc[la * 161 + cc];
    }
}

// ---------------- overflow spill (rare; exact full window) ----------------
__global__ __launch_bounds__(256) void k_spill(const uint4* __restrict__ ovf,
                                               const int* __restrict__ ovfc,
                                               float* __restrict__ out) {
    int n = min(*ovfc, OVF_CAP);
    const float CZ[4] = {0.92387953251f, 0.38268343236f, -0.38268343236f, -0.92387953251f};
    const float SZ[4] = {0.38268343236f, 0.92387953251f, 0.92387953251f, 0.38268343236f};
    for (int idx = blockIdx.x * 256 + threadIdx.x; idx < n; idx += gridDim.x * 256) {
        uint4 e = ovf[idx];
        if (e.w == 0u) {   // radial
            float d = 0.8f + (float)(e.x & 0xffffu) * (4.4f / 65535.0f);
            float coef = 0.25f * (float)(e.x >> 16) * (1.0f / 65535.0f);
            int sp = (int)((e.y >> 6) & 3u), bb = (int)((e.y >> 8) & 1u);
            float* base = out + (size_t)e.z * OUTC + 16 + sp * 32 + bb;
            for (int k = 0; k < 16; ++k) {
                float delta = d - (0.8f + 0.275f * (float)k);
                float v = coef * __expf(-16.0f * delta * delta);
                if (v > 1e-6f) unsafeAtomicAdd(base + k * 2, v);
            }
        } else {           // angular
            float th    = (float)(e.x & 0xffffu) * (3.14159265358979f / 65535.0f);
            float d12   = 0.8f + (float)(e.x >> 16) * (2.7f / 65535.0f);
            float scale = (float)(e.y & 0xffffu) * (2.0f / 65535.0f);
            int pair = (int)((e.y >> 22) & 15u);
            float* base = out + (size_t)e.z * OUTC + 144 + pair * 16;
            float sth, cth;
            __sincosf(th, &sth, &cth);
            for (int zz = 0; zz < 4; ++zz) {
                float x = 0.5f + 0.5f * (cth * CZ[zz] + sth * SZ[zz]);
                float x2 = x * x, x4 = x2 * x2, x8 = x4 * x4, x16 = x8 * x8;
                float f1 = x16 * x16;
                for (int a = 0; a < 4; ++a) {
                    float da = d12 - (0.8f + 0.675f * (float)a);
                    float v = __expf(-8.0f * da * da) * scale * f1;
                    if (v > 1e-6f) unsafeAtomicAdd(base + a * 4 + zz, v);
                }
            }
        }
    }
}

// ================= fallback (round-1 atomic path) =================
__global__ __launch_bounds__(256) void k_init_fb(const float* __restrict__ ecfp,
                                                 float* __restrict__ out, int total4) {
    int i = blockIdx.x * 256 + threadIdx.x;
    if (i >= total4) return;
    int row = i / 76, c4 = i - row * 76;
    float4 v = make_float4(0.f, 0.f, 0.f, 0.f);
    if (c4 < 4) v = ((const float4*)ecfp)[row * 4 + c4];
    ((float4*)out)[i] = v;
}

__global__ __launch_bounds__(256) void k_radial_fb(const float* __restrict__ dist,
                                                   const float* __restrict__ sw,
                                                   const int* __restrict__ bond_order,
                                                   const int* __restrict__ esrc,
                                                   const int* __restrict__ edst,
                                                   const int* __restrict__ species,
                                                   float* __restrict__ out, int e_rad) {
    int e = blockIdx.x * 256 + threadIdx.x;
    if (e >= e_rad) return;
    float d = dist[e], s = sw[e];
    int bo = bond_order[e];
    int bb = (bo == 3 || bo == 5) ? 1 : 0;
    int z = species[edst[e]];
    int sp = (z == 6) ? 1 : (z == 7) ? 2 : (z == 8) ? 3 : 0;
    float* base = out + (size_t)esrc[e] * OUTC + 16 + sp * 32 + bb;
    float coef = 0.25f * s;
#pragma unroll
    for (int r = 0; r < 16; ++r) {
        float delta = d - (0.8f + 0.275f * (float)r);
        float v = coef * __expf(-16.0f * delta * delta);
        if (v > 6e-7f) unsafeAtomicAdd(base + r * 2, v);
    }
}

__global__ __launch_bounds__(256) void k_ang_fb(const float* __restrict__ angles,
                                                const float* __restrict__ angd,
                                                const float* __restrict__ angsw,
                                                const int* __restrict__ aedst,
                                                const int* __restrict__ species,
                                                const int* __restrict__ central,
                                                const int* __restrict__ psrc,
                                                const int* __restrict__ pdst,
                                                float* __restrict__ out, int n_pairs) {
    int p = blockIdx.x * 256 + threadIdx.x;
    if (p >= n_pairs) return;
    int is = psrc[p], it = pdst[p];
    float th = angles[p];
    float d12 = 0.5f * (angd[is] + angd[it]);
    float scale = 2.0f * angsw[is] * angsw[it];
    int zs = species[aedst[is]], zt = species[aedst[it]];
    int sps = (zs == 6) ? 1 : (zs == 7) ? 2 : (zs == 8) ? 3 : 0;
    int spt = (zt == 6) ? 1 : (zt == 7) ? 2 : (zt == 8) ? 3 : 0;
    int i = min(sps, spt), j = max(sps, spt);
    int pair = i * 4 - (i * (i - 1)) / 2 + (j - i);
    float sth, cth;
    __sincosf(th, &sth, &cth);
    const float CZ[4] = {0.92387953251f, 0.38268343236f, -0.38268343236f, -0.92387953251f};
    const float SZ[4] = {0.38268343236f, 0.92387953251f, 0.92387953251f, 0.38268343236f};
    float f1[4];
#pragma unroll
    for (int zz = 0; zz < 4; ++zz) {
        float x = 0.5f + 0.5f * (cth * CZ[zz] + sth * SZ[zz]);
        float x2 = x * x, x4 = x2 * x2, x8 = x4 * x4, x16 = x8 * x8;
        f1[zz] = x16 * x16;
    }
    float* base = out + (size_t)central[p] * OUTC + 144 + pair * 16;
#pragma unroll
    for (int a = 0; a < 4; ++a) {
        float da = d12 - (0.8f + 0.675f * (float)a);
        float f2 = __expf(-8.0f * da * da) * scale;
#pragma unroll
        for (int zz = 0; zz < 4; ++zz) {
            float v = f2 * f1[zz];
            if (v > 6e-7f) unsafeAtomicAdd(base + a * 4 + zz, v);
        }
    }
}

extern "C" void kernel_launch(void* const* d_in, const int* in_sizes, int n_in,
                              void* d_out, int out_size, void* d_ws, size_t ws_size,
                              hipStream_t stream) {
    const float* ecfp      = (const float*)d_in[0];
    const float* distances = (const float*)d_in[1];
    const float* sw        = (const float*)d_in[2];
    const float* angles    = (const float*)d_in[3];
    const float* angd      = (const float*)d_in[4];
    const float* angsw     = (const float*)d_in[5];
    const int*   species   = (const int*)d_in[6];
    const int*   bond_ord  = (const int*)d_in[7];
    const int*   edge_src  = (const int*)d_in[8];
    const int*   edge_dst  = (const int*)d_in[9];
    const int*   aedst     = (const int*)d_in[10];
    const int*   central   = (const int*)d_in[11];
    const int*   angle_src = (const int*)d_in[12];
    const int*   angle_dst = (const int*)d_in[13];
    float* out = (float*)d_out;

    const int e_rad   = in_sizes[1];
    const int n_pairs = in_sizes[3];
    const int e_ang   = in_sizes[4];
    const int n_atoms = in_sizes[6];

    const int NB = (n_atoms + 63) / 64;   // 64-atom bins

    size_t pay_bytes  = (size_t)NB * CAP * 8;
    size_t erec_bytes = ((size_t)e_ang * 4 + 15) & ~(size_t)15;
    size_t ovf_bytes  = (size_t)OVF_CAP * 16;
    size_t need = pay_bytes + erec_bytes + ovf_bytes + (size_t)(2 * NB + 1) * 4;

    bool cap_ok = (NB <= NBK) &&
                  (e_rad  <= (size_t)NB * (CAP - 256)) &&
                  (n_pairs <= (size_t)NB * (CAP - 256));

    if (ws_size >= need && cap_ok) {
        uint2*    payload = (uint2*)d_ws;
        unsigned* erec    = (unsigned*)((char*)d_ws + pay_bytes);
        uint4*    ovf     = (uint4*)((char*)d_ws + pay_bytes + erec_bytes);
        int*      gcntR   = (int*)((char*)ovf + ovf_bytes);
        int*      gcntA   = gcntR + NB;
        int*      ovfc    = gcntA + NB;

        const int span = SC_F * 512;   // 8 iterations, single flush per block
        int gridR = (e_rad + span - 1) / span;
        int gridA = (n_pairs + span - 1) / span;

        int total4 = n_atoms * 4;
        int nz = 2 * NB + 1;
        int prepN = max(e_ang, max(total4, nz));
        k_prep<<<(prepN + 255) / 256, 256, 0, stream>>>(angd, angsw, aedst, species,
                                                        erec, e_ang, ecfp, out, total4,
                                                        gcntR, nz);
        k_scatter_rad<<<gridR, 512, 0, stream>>>(distances, sw, bond_ord, edge_src,
                                                 edge_dst, species, gcntR, payload,
                                                 ovf, ovfc, e_rad, span, NB);
        k_accum_rad<<<NB, 512, 0, stream>>>(payload, gcntR, out, n_atoms);
        k_scatter_ang<<<gridA, 512, 0, stream>>>(angles, erec, central, angle_src,
                                                 angle_dst, gcntA, payload,
                                                 ovf, ovfc, n_pairs, span, NB);
        k_accum_ang<<<NB, 512, 0, stream>>>(payload, gcntA, out, n_atoms);
        k_spill<<<16, 256, 0, stream>>>(ovf, ovfc, out);
    } else {
        int total4 = n_atoms * (OUTC / 4);
        k_init_fb<<<(total4 + 255) / 256, 256, 0, stream>>>(ecfp, out, total4);
        k_radial_fb<<<(e_rad + 255) / 256, 256, 0, stream>>>(distances, sw, bond_ord,
                                                             edge_src, edge_dst, species,
                                                             out, e_rad);
        k_ang_fb<<<(n_pairs + 255) / 256, 256, 0, stream>>>(angles, angd, angsw, aedst,
                                                            species, central, angle_src,
                                                            angle_dst, out, n_pairs);
    }
}

// Round 11
// 219.161 us; speedup vs baseline: 1.1797x; 1.1797x over previous
//
#include <hip/hip_runtime.h>
#include <math.h>

#define OUTC 304
#define NBK  784         // max 64-atom bins (>= ceil(50000/64)=782)
#define CAP  3072        // payload slots per bin (lambda ~2558 at 2M items)
#define SC_K 12          // LDS staging depth per bucket
#define SC_F 8           // flush every SC_F iterations (lambda ~5.2/bucket)
#define OVF_CAP 65536

// ---------------- fused prep: zero counters + ecfp copy + angular edge records ----------------
__global__ __launch_bounds__(256) void k_prep(const float* __restrict__ angd,
                                              const float* __restrict__ angsw,
                                              const int* __restrict__ aedst,
                                              const int* __restrict__ species,
                                              unsigned* __restrict__ erec, int e_ang,
                                              const float* __restrict__ ecfp,
                                              float* __restrict__ out, int total4,
                                              int* __restrict__ gcnt, int nz) {
    int i = blockIdx.x * 256 + threadIdx.x;
    if (i < nz) gcnt[i] = 0;
    if (i < total4) {
        int row = i >> 2, c4 = i & 3;
        ((float4*)out)[row * (OUTC / 4) + c4] = ((const float4*)ecfp)[i];
    }
    if (i < e_ang) {
        int z = species[aedst[i]];
        unsigned sp = (z == 6) ? 1u : (z == 7) ? 2u : (z == 8) ? 3u : 0u;
        float d = angd[i], s = angsw[i];
        unsigned dq = (unsigned)fminf(fmaxf((d - 0.8f) * (4095.0f / 2.7f) + 0.5f, 0.f), 4095.f);
        unsigned sq = (unsigned)fminf(fmaxf(s * 16383.0f + 0.5f, 0.f), 16383.f);
        erec[i] = dq | (sq << 12) | (sp << 26);
    }
}

// ============ LDS-staged counting scatter (radial), 64-atom buckets ============
// payload: x = dq16|sq16 ; y = loc6 | sp2<<6 | bb1<<8
// Owner-computes flush (r10 lesson): thread t drains buckets 2t,2t+1 directly —
// no block prefix-scan, no binary search, 2 barriers per flush.
__global__ __launch_bounds__(512) void k_scatter_rad(
        const float* __restrict__ dist, const float* __restrict__ sw,
        const int* __restrict__ bond_order, const int* __restrict__ esrc,
        const int* __restrict__ edst, const int* __restrict__ species,
        int* __restrict__ gcnt, uint2* __restrict__ payload,
        uint4* __restrict__ ovf, int* __restrict__ ovfc,
        int n, int span, int nb) {
    __shared__ uint2 stg[NBK * SC_K];
    __shared__ int lcnt[NBK];
    const int tid = threadIdx.x;
    for (int i = tid; i < nb; i += 512) lcnt[i] = 0;
    __syncthreads();
    int base = blockIdx.x * span, end = min(base + span, n);
    if (base >= end) return;
    int pend = 0;
    for (int i0 = base; i0 < end; i0 += 512) {
        int e = i0 + tid;
        if (e < end) {
            float d = dist[e];
            float s = sw[e];
            int bo = bond_order[e];
            unsigned bb = (bo == 3 || bo == 5) ? 1u : 0u;
            int z = species[edst[e]];
            unsigned sp = (z == 6) ? 1u : (z == 7) ? 2u : (z == 8) ? 3u : 0u;
            int c = esrc[e];
            unsigned dq = (unsigned)fminf(fmaxf((d - 0.8f) * (65535.0f / 4.4f) + 0.5f, 0.f), 65535.f);
            unsigned sq = (unsigned)fminf(fmaxf(s * 65535.0f + 0.5f, 0.f), 65535.f);
            uint2 pl;
            pl.x = dq | (sq << 16);
            pl.y = (unsigned)(c & 63) | (sp << 6) | (bb << 8);
            int b = c >> 6;
            int slot = atomicAdd(&lcnt[b], 1);
            if (slot < SC_K) stg[b * SC_K + slot] = pl;
            else { int oi = atomicAdd(ovfc, 1); if (oi < OVF_CAP) ovf[oi] = make_uint4(pl.x, pl.y, (unsigned)c, 0u); }
        }
        if (++pend == SC_F || i0 + 512 >= end) {
            pend = 0;
            __syncthreads();
#pragma unroll
            for (int q = 0; q < 2; ++q) {
                int b = 2 * tid + q;
                if (b < nb) {
                    int c = min(lcnt[b], SC_K);
                    if (c > 0) {
                        int gbase = atomicAdd(&gcnt[b], c);
                        const uint2* sp2 = &stg[b * SC_K];
                        uint2* pp = payload + (size_t)b * CAP;
                        for (int k = 0; k < c; ++k) {
                            int gpos = gbase + k;
                            uint2 pl = sp2[k];
                            if (gpos < CAP) pp[gpos] = pl;
                            else { int oi = atomicAdd(ovfc, 1); if (oi < OVF_CAP) ovf[oi] = make_uint4(pl.x, pl.y, (unsigned)(b * 64 + (pl.y & 63u)), 0u); }
                        }
                    }
                    lcnt[b] = 0;
                }
            }
            __syncthreads();
        }
    }
}

// ============ LDS-staged counting scatter (angular), 64-atom buckets ============
// payload: x = tq16|dq16 ; y = sq16 | loc6<<16 | pair4<<22
__global__ __launch_bounds__(512) void k_scatter_ang(
        const float* __restrict__ angles, const unsigned* __restrict__ erec,
        const int* __restrict__ central, const int* __restrict__ psrc,
        const int* __restrict__ pdst,
        int* __restrict__ gcnt, uint2* __restrict__ payload,
        uint4* __restrict__ ovf, int* __restrict__ ovfc,
        int n, int span, int nb) {
    __shared__ uint2 stg[NBK * SC_K];
    __shared__ int lcnt[NBK];
    const int tid = threadIdx.x;
    for (int i = tid; i < nb; i += 512) lcnt[i] = 0;
    __syncthreads();
    int base = blockIdx.x * span, end = min(base + span, n);
    if (base >= end) return;
    int pend = 0;
    for (int i0 = base; i0 < end; i0 += 512) {
        int p = i0 + tid;
        if (p < end) {
            unsigned rs = erec[psrc[p]];
            unsigned rt = erec[pdst[p]];
            float dsrc = 0.8f + (float)(rs & 0xfffu) * (2.7f / 4095.0f);
            float dtgt = 0.8f + (float)(rt & 0xfffu) * (2.7f / 4095.0f);
            float ss = (float)((rs >> 12) & 0x3fffu) * (1.0f / 16383.0f);
            float st = (float)((rt >> 12) & 0x3fffu) * (1.0f / 16383.0f);
            int sps = (int)(rs >> 26), spt = (int)(rt >> 26);
            int i = min(sps, spt), j = max(sps, spt);
            unsigned pair = (unsigned)(i * 4 - (i * (i - 1)) / 2 + (j - i));
            float d12 = 0.5f * (dsrc + dtgt);
            float scale = 2.0f * ss * st;
            float th = angles[p];
            int c = central[p];
            unsigned tq = (unsigned)fminf(fmaxf(th * (65535.0f / 3.14159265358979f) + 0.5f, 0.f), 65535.f);
            unsigned dq = (unsigned)fminf(fmaxf((d12 - 0.8f) * (65535.0f / 2.7f) + 0.5f, 0.f), 65535.f);
            unsigned sq = (unsigned)fminf(fmaxf(scale * (65535.0f / 2.0f) + 0.5f, 0.f), 65535.f);
            uint2 pl;
            pl.x = tq | (dq << 16);
            pl.y = sq | ((unsigned)(c & 63) << 16) | (pair << 22);
            int b = c >> 6;
            int slot = atomicAdd(&lcnt[b], 1);
            if (slot < SC_K) stg[b * SC_K + slot] = pl;
            else { int oi = atomicAdd(ovfc, 1); if (oi < OVF_CAP) ovf[oi] = make_uint4(pl.x, pl.y, (unsigned)c, 1u); }
        }
        if (++pend == SC_F || i0 + 512 >= end) {
            pend = 0;
            __syncthreads();
#pragma unroll
            for (int q = 0; q < 2; ++q) {
                int b = 2 * tid + q;
                if (b < nb) {
                    int c = min(lcnt[b], SC_K);
                    if (c > 0) {
                        int gbase = atomicAdd(&gcnt[b], c);
                        const uint2* sp2 = &stg[b * SC_K];
                        uint2* pp = payload + (size_t)b * CAP;
                        for (int k = 0; k < c; ++k) {
                            int gpos = gbase + k;
                            uint2 pl = sp2[k];
                            if (gpos < CAP) pp[gpos] = pl;
                            else { int oi = atomicAdd(ovfc, 1); if (oi < OVF_CAP) ovf[oi] = make_uint4(pl.x, pl.y, (unsigned)(b * 64 + ((pl.y >> 16) & 63u)), 1u); }
                        }
                    }
                    lcnt[b] = 0;
                }
            }
            __syncthreads();
        }
    }
}

// ---------------- per-item accumulate helpers: window + per-lane threshold ----------------
#define VTHR 1.5e-3f

__device__ __forceinline__ void proc_rad(uint2 pl, float* acc) {
    float d = 0.8f + (float)(pl.x & 0xffffu) * (4.4f / 65535.0f);
    float coef = 0.25f * (float)(pl.x >> 16) * (1.0f / 65535.0f);
    int bidx = (int)(pl.y & 63u) * 129 + (int)((pl.y >> 6) & 3u) * 32 + (int)((pl.y >> 8) & 1u);
    int c0 = (int)((d - 0.8f) * (1.0f / 0.275f)) - 1;
    c0 = max(0, min(12, c0));
    float dd = d - (0.8f + 0.275f * (float)c0);
    float* ap = acc + bidx + c0 * 2;
#pragma unroll
    for (int kk = 0; kk < 4; ++kk) {
        float delta = dd - 0.275f * (float)kk;
        float v = coef * __expf(-16.0f * delta * delta);
        if (v > VTHR) atomicAdd(&ap[kk * 2], v);
    }
}

__device__ __forceinline__ void proc_ang(uint2 pl, float* acc) {
    float th    = (float)(pl.x & 0xffffu) * (3.14159265358979f / 65535.0f);
    float d12   = 0.8f + (float)(pl.x >> 16) * (2.7f / 65535.0f);
    float scale = (float)(pl.y & 0xffffu) * (2.0f / 65535.0f);
    int rowb = (int)((pl.y >> 16) & 63u) * 161 + (int)((pl.y >> 22) & 15u) * 16;
    int z0 = (int)(th * (4.0f / 3.14159265358979f) - 0.5f);
    z0 = max(0, min(2, z0));
    float cz = (z0 == 0) ? 0.92387953251f : ((z0 == 1) ? 0.38268343236f : -0.38268343236f);
    float sz = (z0 == 0) ? 0.38268343236f : 0.92387953251f;
    float sth, cth;
    __sincosf(th, &sth, &cth);
    float cq = cth * cz + sth * sz;
    float sq = sth * cz - cth * sz;
    float xa = 0.5f + 0.5f * cq;
    float cq1 = 0.70710678119f * (cq + sq);
    float xb = 0.5f + 0.5f * cq1;
    float x2, x4, x8, x16, f1a, f1b;
    x2 = xa * xa; x4 = x2 * x2; x8 = x4 * x4; x16 = x8 * x8; f1a = x16 * x16;
    x2 = xb * xb; x4 = x2 * x2; x8 = x4 * x4; x16 = x8 * x8; f1b = x16 * x16;
    int ar = (int)((d12 - 0.8f) * (1.0f / 0.675f) + 0.5f);
    int a0 = max(0, min(1, ar - 1));
    float da = d12 - (0.8f + 0.675f * (float)a0);
    float* ap = acc + rowb + a0 * 4 + z0;
#pragma unroll
    for (int aa = 0; aa < 3; ++aa) {
        float delta = da - 0.675f * (float)aa;
        float f2 = __expf(-8.0f * delta * delta) * scale;
        float v0 = f2 * f1a;
        float v1 = f2 * f1b;
        if (v0 > VTHR) atomicAdd(&ap[aa * 4], v0);
        if (v1 > VTHR) atomicAdd(&ap[aa * 4 + 1], v1);
    }
}

// ---------------- radial accumulate: one 64-atom bin per block ----------------
__global__ __launch_bounds__(512) void k_accum_rad(const uint2* __restrict__ payload,
                                                   const int* __restrict__ gcnt,
                                                   float* __restrict__ out, int n_atoms) {
    __shared__ float acc[64 * 129];   // 33 KB, padded stride
    int b = blockIdx.x;
    for (int i = threadIdx.x; i < 64 * 129; i += 512) acc[i] = 0.f;
    __syncthreads();
    int len = min(gcnt[b], CAP);
    const uint2* pp = payload + (size_t)b * CAP;
    for (int r = threadIdx.x; r < len; r += 512) proc_rad(pp[r], acc);
    __syncthreads();
    int a0 = b * 64;
    for (int i = threadIdx.x; i < 64 * 128; i += 512) {
        int la = i >> 7, cc = i & 127;
        int atom = a0 + la;
        if (atom < n_atoms) out[(size_t)atom * OUTC + 16 + cc] = acc[la * 129 + cc];
    }
}

// ---------------- angular accumulate: one 64-atom bin per block ----------------
__global__ __launch_bounds__(512) void k_accum_ang(const uint2* __restrict__ payload,
                                                   const int* __restrict__ gcnt,
                                                   float* __restrict__ out, int n_atoms) {
    __shared__ float acc[64 * 161];   // 41 KB, padded stride
    int b = blockIdx.x;
    for (int i = threadIdx.x; i < 64 * 161; i += 512) acc[i] = 0.f;
    __syncthreads();
    int len = min(gcnt[b], CAP);
    const uint2* pp = payload + (size_t)b * CAP;
    for (int r = threadIdx.x; r < len; r += 512) proc_ang(pp[r], acc);
    __syncthreads();
    int a0 = b * 64;
    for (int i = threadIdx.x; i < 64 * 160; i += 512) {
        int la = i / 160, cc = i - la * 160;
        int atom = a0 + la;
        if (atom < n_atoms) out[(size_t)atom * OUTC + 144 + cc] = acc[la * 161 + cc];
    }
}

// ---------------- overflow spill (rare; exact full window) ----------------
__global__ __launch_bounds__(256) void k_spill(const uint4* __restrict__ ovf,
                                               const int* __restrict__ ovfc,
                                               float* __restrict__ out) {
    int n = min(*ovfc, OVF_CAP);
    const float CZ[4] = {0.92387953251f, 0.38268343236f, -0.38268343236f, -0.92387953251f};
    const float SZ[4] = {0.38268343236f, 0.92387953251f, 0.92387953251f, 0.38268343236f};
    for (int idx = blockIdx.x * 256 + threadIdx.x; idx < n; idx += gridDim.x * 256) {
        uint4 e = ovf[idx];
        if (e.w == 0u) {   // radial
            float d = 0.8f + (float)(e.x & 0xffffu) * (4.4f / 65535.0f);
            float coef = 0.25f * (float)(e.x >> 16) * (1.0f / 65535.0f);
            int sp = (int)((e.y >> 6) & 3u), bb = (int)((e.y >> 8) & 1u);
            float* base = out + (size_t)e.z * OUTC + 16 + sp * 32 + bb;
            for (int k = 0; k < 16; ++k) {
                float delta = d - (0.8f + 0.275f * (float)k);
                float v = coef * __expf(-16.0f * delta * delta);
                if (v > 1e-6f) unsafeAtomicAdd(base + k * 2, v);
            }
        } else {           // angular
            float th    = (float)(e.x & 0xffffu) * (3.14159265358979f / 65535.0f);
            float d12   = 0.8f + (float)(e.x >> 16) * (2.7f / 65535.0f);
            float scale = (float)(e.y & 0xffffu) * (2.0f / 65535.0f);
            int pair = (int)((e.y >> 22) & 15u);
            float* base = out + (size_t)e.z * OUTC + 144 + pair * 16;
            float sth, cth;
            __sincosf(th, &sth, &cth);
            for (int zz = 0; zz < 4; ++zz) {
                float x = 0.5f + 0.5f * (cth * CZ[zz] + sth * SZ[zz]);
                float x2 = x * x, x4 = x2 * x2, x8 = x4 * x4, x16 = x8 * x8;
                float f1 = x16 * x16;
                for (int a = 0; a < 4; ++a) {
                    float da = d12 - (0.8f + 0.675f * (float)a);
                    float v = __expf(-8.0f * da * da) * scale * f1;
                    if (v > 1e-6f) unsafeAtomicAdd(base + a * 4 + zz, v);
                }
            }
        }
    }
}

// ================= fallback (round-1 atomic path) =================
__global__ __launch_bounds__(256) void k_init_fb(const float* __restrict__ ecfp,
                                                 float* __restrict__ out, int total4) {
    int i = blockIdx.x * 256 + threadIdx.x;
    if (i >= total4) return;
    int row = i / 76, c4 = i - row * 76;
    float4 v = make_float4(0.f, 0.f, 0.f, 0.f);
    if (c4 < 4) v = ((const float4*)ecfp)[row * 4 + c4];
    ((float4*)out)[i] = v;
}

__global__ __launch_bounds__(256) void k_radial_fb(const float* __restrict__ dist,
                                                   const float* __restrict__ sw,
                                                   const int* __restrict__ bond_order,
                                                   const int* __restrict__ esrc,
                                                   const int* __restrict__ edst,
                                                   const int* __restrict__ species,
                                                   float* __restrict__ out, int e_rad) {
    int e = blockIdx.x * 256 + threadIdx.x;
    if (e >= e_rad) return;
    float d = dist[e], s = sw[e];
    int bo = bond_order[e];
    int bb = (bo == 3 || bo == 5) ? 1 : 0;
    int z = species[edst[e]];
    int sp = (z == 6) ? 1 : (z == 7) ? 2 : (z == 8) ? 3 : 0;
    float* base = out + (size_t)esrc[e] * OUTC + 16 + sp * 32 + bb;
    float coef = 0.25f * s;
#pragma unroll
    for (int r = 0; r < 16; ++r) {
        float delta = d - (0.8f + 0.275f * (float)r);
        float v = coef * __expf(-16.0f * delta * delta);
        if (v > 6e-7f) unsafeAtomicAdd(base + r * 2, v);
    }
}

__global__ __launch_bounds__(256) void k_ang_fb(const float* __restrict__ angles,
                                                const float* __restrict__ angd,
                                                const float* __restrict__ angsw,
                                                const int* __restrict__ aedst,
                                                const int* __restrict__ species,
                                                const int* __restrict__ central,
                                                const int* __restrict__ psrc,
                                                const int* __restrict__ pdst,
                                                float* __restrict__ out, int n_pairs) {
    int p = blockIdx.x * 256 + threadIdx.x;
    if (p >= n_pairs) return;
    int is = psrc[p], it = pdst[p];
    float th = angles[p];
    float d12 = 0.5f * (angd[is] + angd[it]);
    float scale = 2.0f * angsw[is] * angsw[it];
    int zs = species[aedst[is]], zt = species[aedst[it]];
    int sps = (zs == 6) ? 1 : (zs == 7) ? 2 : (zs == 8) ? 3 : 0;
    int spt = (zt == 6) ? 1 : (zt == 7) ? 2 : (zt == 8) ? 3 : 0;
    int i = min(sps, spt), j = max(sps, spt);
    int pair = i * 4 - (i * (i - 1)) / 2 + (j - i);
    float sth, cth;
    __sincosf(th, &sth, &cth);
    const float CZ[4] = {0.92387953251f, 0.38268343236f, -0.38268343236f, -0.92387953251f};
    const float SZ[4] = {0.38268343236f, 0.92387953251f, 0.92387953251f, 0.38268343236f};
    float f1[4];
#pragma unroll
    for (int zz = 0; zz < 4; ++zz) {
        float x = 0.5f + 0.5f * (cth * CZ[zz] + sth * SZ[zz]);
        float x2 = x * x, x4 = x2 * x2, x8 = x4 * x4, x16 = x8 * x8;
        f1[zz] = x16 * x16;
    }
    float* base = out + (size_t)central[p] * OUTC + 144 + pair * 16;
#pragma unroll
    for (int a = 0; a < 4; ++a) {
        float da = d12 - (0.8f + 0.675f * (float)a);
        float f2 = __expf(-8.0f * da * da) * scale;
#pragma unroll
        for (int zz = 0; zz < 4; ++zz) {
            float v = f2 * f1[zz];
            if (v > 6e-7f) unsafeAtomicAdd(base + a * 4 + zz, v);
        }
    }
}

extern "C" void kernel_launch(void* const* d_in, const int* in_sizes, int n_in,
                              void* d_out, int out_size, void* d_ws, size_t ws_size,
                              hipStream_t stream) {
    const float* ecfp      = (const float*)d_in[0];
    const float* distances = (const float*)d_in[1];
    const float* sw        = (const float*)d_in[2];
    const float* angles    = (const float*)d_in[3];
    const float* angd      = (const float*)d_in[4];
    const float* angsw     = (const float*)d_in[5];
    const int*   species   = (const int*)d_in[6];
    const int*   bond_ord  = (const int*)d_in[7];
    const int*   edge_src  = (const int*)d_in[8];
    const int*   edge_dst  = (const int*)d_in[9];
    const int*   aedst     = (const int*)d_in[10];
    const int*   central   = (const int*)d_in[11];
    const int*   angle_src = (const int*)d_in[12];
    const int*   angle_dst = (const int*)d_in[13];
    float* out = (float*)d_out;

    const int e_rad   = in_sizes[1];
    const int n_pairs = in_sizes[3];
    const int e_ang   = in_sizes[4];
    const int n_atoms = in_sizes[6];

    const int NB = (n_atoms + 63) / 64;   // 64-atom bins

    size_t pay_bytes  = (size_t)NB * CAP * 8;
    size_t erec_bytes = ((size_t)e_ang * 4 + 15) & ~(size_t)15;
    size_t ovf_bytes  = (size_t)OVF_CAP * 16;
    size_t need = pay_bytes + erec_bytes + ovf_bytes + (size_t)(2 * NB + 1) * 4;

    bool cap_ok = (NB <= NBK) &&
                  (e_rad  <= (size_t)NB * (CAP - 256)) &&
                  (n_pairs <= (size_t)NB * (CAP - 256));

    if (ws_size >= need && cap_ok) {
        uint2*    payload = (uint2*)d_ws;
        unsigned* erec    = (unsigned*)((char*)d_ws + pay_bytes);
        uint4*    ovf     = (uint4*)((char*)d_ws + pay_bytes + erec_bytes);
        int*      gcntR   = (int*)((char*)ovf + ovf_bytes);
        int*      gcntA   = gcntR + NB;
        int*      ovfc    = gcntA + NB;

        const int span = SC_F * 2 * 512;   // 16 iterations, 2 flushes per block
        int gridR = (e_rad + span - 1) / span;
        int gridA = (n_pairs + span - 1) / span;

        int total4 = n_atoms * 4;
        int nz = 2 * NB + 1;
        int prepN = max(e_ang, max(total4, nz));
        k_prep<<<(prepN + 255) / 256, 256, 0, stream>>>(angd, angsw, aedst, species,
                                                        erec, e_ang, ecfp, out, total4,
                                                        gcntR, nz);
        k_scatter_rad<<<gridR, 512, 0, stream>>>(distances, sw, bond_ord, edge_src,
                                                 edge_dst, species, gcntR, payload,
                                                 ovf, ovfc, e_rad, span, NB);
        k_accum_rad<<<NB, 512, 0, stream>>>(payload, gcntR, out, n_atoms);
        k_scatter_ang<<<gridA, 512, 0, stream>>>(angles, erec, central, angle_src,
                                                 angle_dst, gcntA, payload,
                                                 ovf, ovfc, n_pairs, span, NB);
        k_accum_ang<<<NB, 512, 0, stream>>>(payload, gcntA, out, n_atoms);
        k_spill<<<16, 256, 0, stream>>>(ovf, ovfc, out);
    } else {
        int total4 = n_atoms * (OUTC / 4);
        k_init_fb<<<(total4 + 255) / 256, 256, 0, stream>>>(ecfp, out, total4);
        k_radial_fb<<<(e_rad + 255) / 256, 256, 0, stream>>>(distances, sw, bond_ord,
                                                             edge_src, edge_dst, species,
                                                             out, e_rad);
        k_ang_fb<<<(n_pairs + 255) / 256, 256, 0, stream>>>(angles, angd, angsw, aedst,
                                                            species, central, angle_src,
                                                            angle_dst, out, n_pairs);
    }
}

// Round 12
// 178.708 us; speedup vs baseline: 1.4467x; 1.2264x over previous
//
#include <hip/hip_runtime.h>
#include <math.h>

#define OUTC 304
#define NBK  784         // max 64-atom bins (>= ceil(50000/64)=782)
#define CAP  3072        // payload slots per bin (lambda ~2558 at 2M items)
#define SC_K 12          // LDS staging depth per bucket
#define SC_F 8           // flush every SC_F iterations (lambda ~5.2/bucket)
#define OVF_CAP 65536

// ---------------- fused prep: zero counters + ecfp copy + angular edge records ----------------
__global__ __launch_bounds__(256) void k_prep(const float* __restrict__ angd,
                                              const float* __restrict__ angsw,
                                              const int* __restrict__ aedst,
                                              const int* __restrict__ species,
                                              unsigned* __restrict__ erec, int e_ang,
                                              const float* __restrict__ ecfp,
                                              float* __restrict__ out, int total4,
                                              int* __restrict__ gcnt, int nz) {
    int i = blockIdx.x * 256 + threadIdx.x;
    if (i < nz) gcnt[i] = 0;
    if (i < total4) {
        int row = i >> 2, c4 = i & 3;
        ((float4*)out)[row * (OUTC / 4) + c4] = ((const float4*)ecfp)[i];
    }
    if (i < e_ang) {
        int z = species[aedst[i]];
        unsigned sp = (z == 6) ? 1u : (z == 7) ? 2u : (z == 8) ? 3u : 0u;
        float d = angd[i], s = angsw[i];
        unsigned dq = (unsigned)fminf(fmaxf((d - 0.8f) * (4095.0f / 2.7f) + 0.5f, 0.f), 4095.f);
        unsigned sq = (unsigned)fminf(fmaxf(s * 16383.0f + 0.5f, 0.f), 16383.f);
        erec[i] = dq | (sq << 12) | (sp << 26);
    }
}

// ================= scatter device bodies (owner-computes flush, r11) =================
__device__ __forceinline__ void scatter_rad_dev(
        const float* __restrict__ dist, const float* __restrict__ sw,
        const int* __restrict__ bond_order, const int* __restrict__ esrc,
        const int* __restrict__ edst, const int* __restrict__ species,
        int* __restrict__ gcnt, uint2* __restrict__ payload,
        uint4* __restrict__ ovf, int* __restrict__ ovfc,
        int n, int span, int nb, int bid, uint2* stg, int* lcnt) {
    const int tid = threadIdx.x;
    for (int i = tid; i < nb; i += 512) lcnt[i] = 0;
    __syncthreads();
    int base = bid * span, end = min(base + span, n);
    if (base >= end) return;
    int pend = 0;
    for (int i0 = base; i0 < end; i0 += 512) {
        int e = i0 + tid;
        if (e < end) {
            float d = dist[e];
            float s = sw[e];
            int bo = bond_order[e];
            unsigned bb = (bo == 3 || bo == 5) ? 1u : 0u;
            int z = species[edst[e]];
            unsigned sp = (z == 6) ? 1u : (z == 7) ? 2u : (z == 8) ? 3u : 0u;
            int c = esrc[e];
            unsigned dq = (unsigned)fminf(fmaxf((d - 0.8f) * (65535.0f / 4.4f) + 0.5f, 0.f), 65535.f);
            unsigned sq = (unsigned)fminf(fmaxf(s * 65535.0f + 0.5f, 0.f), 65535.f);
            uint2 pl;
            pl.x = dq | (sq << 16);
            pl.y = (unsigned)(c & 63) | (sp << 6) | (bb << 8);
            int b = c >> 6;
            int slot = atomicAdd(&lcnt[b], 1);
            if (slot < SC_K) stg[b * SC_K + slot] = pl;
            else { int oi = atomicAdd(ovfc, 1); if (oi < OVF_CAP) ovf[oi] = make_uint4(pl.x, pl.y, (unsigned)c, 0u); }
        }
        if (++pend == SC_F || i0 + 512 >= end) {
            pend = 0;
            __syncthreads();
#pragma unroll
            for (int q = 0; q < 2; ++q) {
                int b = 2 * tid + q;
                if (b < nb) {
                    int c = min(lcnt[b], SC_K);
                    if (c > 0) {
                        int gbase = atomicAdd(&gcnt[b], c);
                        const uint2* sp2 = &stg[b * SC_K];
                        uint2* pp = payload + (size_t)b * CAP;
                        for (int k = 0; k < c; ++k) {
                            int gpos = gbase + k;
                            uint2 pl = sp2[k];
                            if (gpos < CAP) pp[gpos] = pl;
                            else { int oi = atomicAdd(ovfc, 1); if (oi < OVF_CAP) ovf[oi] = make_uint4(pl.x, pl.y, (unsigned)(b * 64 + (pl.y & 63u)), 0u); }
                        }
                    }
                    lcnt[b] = 0;
                }
            }
            __syncthreads();
        }
    }
}

__device__ __forceinline__ void scatter_ang_dev(
        const float* __restrict__ angles, const unsigned* __restrict__ erec,
        const int* __restrict__ central, const int* __restrict__ psrc,
        const int* __restrict__ pdst,
        int* __restrict__ gcnt, uint2* __restrict__ payload,
        uint4* __restrict__ ovf, int* __restrict__ ovfc,
        int n, int span, int nb, int bid, uint2* stg, int* lcnt) {
    const int tid = threadIdx.x;
    for (int i = tid; i < nb; i += 512) lcnt[i] = 0;
    __syncthreads();
    int base = bid * span, end = min(base + span, n);
    if (base >= end) return;
    int pend = 0;
    for (int i0 = base; i0 < end; i0 += 512) {
        int p = i0 + tid;
        if (p < end) {
            unsigned rs = erec[psrc[p]];
            unsigned rt = erec[pdst[p]];
            float dsrc = 0.8f + (float)(rs & 0xfffu) * (2.7f / 4095.0f);
            float dtgt = 0.8f + (float)(rt & 0xfffu) * (2.7f / 4095.0f);
            float ss = (float)((rs >> 12) & 0x3fffu) * (1.0f / 16383.0f);
            float st = (float)((rt >> 12) & 0x3fffu) * (1.0f / 16383.0f);
            int sps = (int)(rs >> 26), spt = (int)(rt >> 26);
            int i = min(sps, spt), j = max(sps, spt);
            unsigned pair = (unsigned)(i * 4 - (i * (i - 1)) / 2 + (j - i));
            float d12 = 0.5f * (dsrc + dtgt);
            float scale = 2.0f * ss * st;
            float th = angles[p];
            int c = central[p];
            unsigned tq = (unsigned)fminf(fmaxf(th * (65535.0f / 3.14159265358979f) + 0.5f, 0.f), 65535.f);
            unsigned dq = (unsigned)fminf(fmaxf((d12 - 0.8f) * (65535.0f / 2.7f) + 0.5f, 0.f), 65535.f);
            unsigned sq = (unsigned)fminf(fmaxf(scale * (65535.0f / 2.0f) + 0.5f, 0.f), 65535.f);
            uint2 pl;
            pl.x = tq | (dq << 16);
            pl.y = sq | ((unsigned)(c & 63) << 16) | (pair << 22);
            int b = c >> 6;
            int slot = atomicAdd(&lcnt[b], 1);
            if (slot < SC_K) stg[b * SC_K + slot] = pl;
            else { int oi = atomicAdd(ovfc, 1); if (oi < OVF_CAP) ovf[oi] = make_uint4(pl.x, pl.y, (unsigned)c, 1u); }
        }
        if (++pend == SC_F || i0 + 512 >= end) {
            pend = 0;
            __syncthreads();
#pragma unroll
            for (int q = 0; q < 2; ++q) {
                int b = 2 * tid + q;
                if (b < nb) {
                    int c = min(lcnt[b], SC_K);
                    if (c > 0) {
                        int gbase = atomicAdd(&gcnt[b], c);
                        const uint2* sp2 = &stg[b * SC_K];
                        uint2* pp = payload + (size_t)b * CAP;
                        for (int k = 0; k < c; ++k) {
                            int gpos = gbase + k;
                            uint2 pl = sp2[k];
                            if (gpos < CAP) pp[gpos] = pl;
                            else { int oi = atomicAdd(ovfc, 1); if (oi < OVF_CAP) ovf[oi] = make_uint4(pl.x, pl.y, (unsigned)(b * 64 + ((pl.y >> 16) & 63u)), 1u); }
                        }
                    }
                    lcnt[b] = 0;
                }
            }
            __syncthreads();
        }
    }
}

// ---------------- per-item accumulate helpers: window + per-lane threshold ----------------
#define VTHR 1.5e-3f

__device__ __forceinline__ void proc_rad(uint2 pl, float* acc) {
    float d = 0.8f + (float)(pl.x & 0xffffu) * (4.4f / 65535.0f);
    float coef = 0.25f * (float)(pl.x >> 16) * (1.0f / 65535.0f);
    int bidx = (int)(pl.y & 63u) * 129 + (int)((pl.y >> 6) & 3u) * 32 + (int)((pl.y >> 8) & 1u);
    int c0 = (int)((d - 0.8f) * (1.0f / 0.275f)) - 1;
    c0 = max(0, min(12, c0));
    float dd = d - (0.8f + 0.275f * (float)c0);
    float* ap = acc + bidx + c0 * 2;
#pragma unroll
    for (int kk = 0; kk < 4; ++kk) {
        float delta = dd - 0.275f * (float)kk;
        float v = coef * __expf(-16.0f * delta * delta);
        if (v > VTHR) atomicAdd(&ap[kk * 2], v);
    }
}

__device__ __forceinline__ void proc_ang(uint2 pl, float* acc) {
    float th    = (float)(pl.x & 0xffffu) * (3.14159265358979f / 65535.0f);
    float d12   = 0.8f + (float)(pl.x >> 16) * (2.7f / 65535.0f);
    float scale = (float)(pl.y & 0xffffu) * (2.0f / 65535.0f);
    int rowb = (int)((pl.y >> 16) & 63u) * 161 + (int)((pl.y >> 22) & 15u) * 16;
    int z0 = (int)(th * (4.0f / 3.14159265358979f) - 0.5f);
    z0 = max(0, min(2, z0));
    float cz = (z0 == 0) ? 0.92387953251f : ((z0 == 1) ? 0.38268343236f : -0.38268343236f);
    float sz = (z0 == 0) ? 0.38268343236f : 0.92387953251f;
    float sth, cth;
    __sincosf(th, &sth, &cth);
    float cq = cth * cz + sth * sz;
    float sq = sth * cz - cth * sz;
    float xa = 0.5f + 0.5f * cq;
    float cq1 = 0.70710678119f * (cq + sq);
    float xb = 0.5f + 0.5f * cq1;
    float x2, x4, x8, x16, f1a, f1b;
    x2 = xa * xa; x4 = x2 * x2; x8 = x4 * x4; x16 = x8 * x8; f1a = x16 * x16;
    x2 = xb * xb; x4 = x2 * x2; x8 = x4 * x4; x16 = x8 * x8; f1b = x16 * x16;
    int ar = (int)((d12 - 0.8f) * (1.0f / 0.675f) + 0.5f);
    int a0 = max(0, min(1, ar - 1));
    float da = d12 - (0.8f + 0.675f * (float)a0);
    float* ap = acc + rowb + a0 * 4 + z0;
#pragma unroll
    for (int aa = 0; aa < 3; ++aa) {
        float delta = da - 0.675f * (float)aa;
        float f2 = __expf(-8.0f * delta * delta) * scale;
        float v0 = f2 * f1a;
        float v1 = f2 * f1b;
        if (v0 > VTHR) atomicAdd(&ap[aa * 4], v0);
        if (v1 > VTHR) atomicAdd(&ap[aa * 4 + 1], v1);
    }
}

// ================= accumulate device bodies =================
__device__ __forceinline__ void accum_rad_dev(const uint2* __restrict__ payload,
                                              const int* __restrict__ gcnt,
                                              float* __restrict__ out, int n_atoms,
                                              int b, float* acc) {
    for (int i = threadIdx.x; i < 64 * 129; i += 512) acc[i] = 0.f;
    __syncthreads();
    int len = min(gcnt[b], CAP);
    const uint2* pp = payload + (size_t)b * CAP;
    for (int r = threadIdx.x; r < len; r += 512) proc_rad(pp[r], acc);
    __syncthreads();
    int a0 = b * 64;
    for (int i = threadIdx.x; i < 64 * 128; i += 512) {
        int la = i >> 7, cc = i & 127;
        int atom = a0 + la;
        if (atom < n_atoms) out[(size_t)atom * OUTC + 16 + cc] = acc[la * 129 + cc];
    }
}

__device__ __forceinline__ void accum_ang_dev(const uint2* __restrict__ payload,
                                              const int* __restrict__ gcnt,
                                              float* __restrict__ out, int n_atoms,
                                              int b, float* acc) {
    for (int i = threadIdx.x; i < 64 * 161; i += 512) acc[i] = 0.f;
    __syncthreads();
    int len = min(gcnt[b], CAP);
    const uint2* pp = payload + (size_t)b * CAP;
    for (int r = threadIdx.x; r < len; r += 512) proc_ang(pp[r], acc);
    __syncthreads();
    int a0 = b * 64;
    for (int i = threadIdx.x; i < 64 * 160; i += 512) {
        int la = i / 160, cc = i - la * 160;
        int atom = a0 + la;
        if (atom < n_atoms) out[(size_t)atom * OUTC + 144 + cc] = acc[la * 161 + cc];
    }
}

// ================= fused kernels (dual-payload path) =================
__global__ __launch_bounds__(512) void k_scatter_fused(
        const float* __restrict__ dist, const float* __restrict__ sw,
        const int* __restrict__ bond_order, const int* __restrict__ esrc,
        const int* __restrict__ edst, const int* __restrict__ species,
        int* __restrict__ gcntR, uint2* __restrict__ payR,
        const float* __restrict__ angles, const unsigned* __restrict__ erec,
        const int* __restrict__ central, const int* __restrict__ psrc,
        const int* __restrict__ pdst,
        int* __restrict__ gcntA, uint2* __restrict__ payA,
        uint4* __restrict__ ovf, int* __restrict__ ovfc,
        int e_rad, int n_pairs, int span, int nb, int gridR, int gridA) {
    __shared__ uint2 stg[NBK * SC_K];
    __shared__ int lcnt[NBK];
    int m = min(gridR, gridA), m2 = 2 * m;
    int bi = (int)blockIdx.x;
    bool ang; int bidx;
    if (bi < m2) { ang = bi & 1; bidx = bi >> 1; }
    else { ang = (gridA > gridR); bidx = m + (bi - m2); }
    if (ang)
        scatter_ang_dev(angles, erec, central, psrc, pdst, gcntA, payA,
                        ovf, ovfc, n_pairs, span, nb, bidx, stg, lcnt);
    else
        scatter_rad_dev(dist, sw, bond_order, esrc, edst, species, gcntR, payR,
                        ovf, ovfc, e_rad, span, nb, bidx, stg, lcnt);
}

__global__ __launch_bounds__(512) void k_accum_fused(const uint2* __restrict__ payR,
                                                     const int* __restrict__ gcntR,
                                                     const uint2* __restrict__ payA,
                                                     const int* __restrict__ gcntA,
                                                     float* __restrict__ out, int n_atoms) {
    __shared__ float acc[64 * 161];   // 41 KB frame shared by both types
    int b = blockIdx.x >> 1;
    if (blockIdx.x & 1) accum_ang_dev(payA, gcntA, out, n_atoms, b, acc);
    else                accum_rad_dev(payR, gcntR, out, n_atoms, b, acc);
}

// ================= sequential-path thin kernels (single payload) =================
__global__ __launch_bounds__(512) void k_scatter_rad(
        const float* __restrict__ dist, const float* __restrict__ sw,
        const int* __restrict__ bond_order, const int* __restrict__ esrc,
        const int* __restrict__ edst, const int* __restrict__ species,
        int* __restrict__ gcnt, uint2* __restrict__ payload,
        uint4* __restrict__ ovf, int* __restrict__ ovfc,
        int n, int span, int nb) {
    __shared__ uint2 stg[NBK * SC_K];
    __shared__ int lcnt[NBK];
    scatter_rad_dev(dist, sw, bond_order, esrc, edst, species, gcnt, payload,
                    ovf, ovfc, n, span, nb, blockIdx.x, stg, lcnt);
}

__global__ __launch_bounds__(512) void k_scatter_ang(
        const float* __restrict__ angles, const unsigned* __restrict__ erec,
        const int* __restrict__ central, const int* __restrict__ psrc,
        const int* __restrict__ pdst,
        int* __restrict__ gcnt, uint2* __restrict__ payload,
        uint4* __restrict__ ovf, int* __restrict__ ovfc,
        int n, int span, int nb) {
    __shared__ uint2 stg[NBK * SC_K];
    __shared__ int lcnt[NBK];
    scatter_ang_dev(angles, erec, central, psrc, pdst, gcnt, payload,
                    ovf, ovfc, n, span, nb, blockIdx.x, stg, lcnt);
}

__global__ __launch_bounds__(512) void k_accum_rad(const uint2* __restrict__ payload,
                                                   const int* __restrict__ gcnt,
                                                   float* __restrict__ out, int n_atoms) {
    __shared__ float acc[64 * 129];
    accum_rad_dev(payload, gcnt, out, n_atoms, blockIdx.x, acc);
}

__global__ __launch_bounds__(512) void k_accum_ang(const uint2* __restrict__ payload,
                                                   const int* __restrict__ gcnt,
                                                   float* __restrict__ out, int n_atoms) {
    __shared__ float acc[64 * 161];
    accum_ang_dev(payload, gcnt, out, n_atoms, blockIdx.x, acc);
}

// ---------------- overflow spill (rare; exact full window) ----------------
__global__ __launch_bounds__(256) void k_spill(const uint4* __restrict__ ovf,
                                               const int* __restrict__ ovfc,
                                               float* __restrict__ out) {
    int n = min(*ovfc, OVF_CAP);
    const float CZ[4] = {0.92387953251f, 0.38268343236f, -0.38268343236f, -0.92387953251f};
    const float SZ[4] = {0.38268343236f, 0.92387953251f, 0.92387953251f, 0.38268343236f};
    for (int idx = blockIdx.x * 256 + threadIdx.x; idx < n; idx += gridDim.x * 256) {
        uint4 e = ovf[idx];
        if (e.w == 0u) {   // radial
            float d = 0.8f + (float)(e.x & 0xffffu) * (4.4f / 65535.0f);
            float coef = 0.25f * (float)(e.x >> 16) * (1.0f / 65535.0f);
            int sp = (int)((e.y >> 6) & 3u), bb = (int)((e.y >> 8) & 1u);
            float* base = out + (size_t)e.z * OUTC + 16 + sp * 32 + bb;
            for (int k = 0; k < 16; ++k) {
                float delta = d - (0.8f + 0.275f * (float)k);
                float v = coef * __expf(-16.0f * delta * delta);
                if (v > 1e-6f) unsafeAtomicAdd(base + k * 2, v);
            }
        } else {           // angular
            float th    = (float)(e.x & 0xffffu) * (3.14159265358979f / 65535.0f);
            float d12   = 0.8f + (float)(e.x >> 16) * (2.7f / 65535.0f);
            float scale = (float)(e.y & 0xffffu) * (2.0f / 65535.0f);
            int pair = (int)((e.y >> 22) & 15u);
            float* base = out + (size_t)e.z * OUTC + 144 + pair * 16;
            float sth, cth;
            __sincosf(th, &sth, &cth);
            for (int zz = 0; zz < 4; ++zz) {
                float x = 0.5f + 0.5f * (cth * CZ[zz] + sth * SZ[zz]);
                float x2 = x * x, x4 = x2 * x2, x8 = x4 * x4, x16 = x8 * x8;
                float f1 = x16 * x16;
                for (int a = 0; a < 4; ++a) {
                    float da = d12 - (0.8f + 0.675f * (float)a);
                    float v = __expf(-8.0f * da * da) * scale * f1;
                    if (v > 1e-6f) unsafeAtomicAdd(base + a * 4 + zz, v);
                }
            }
        }
    }
}

// ================= fallback (round-1 atomic path) =================
__global__ __launch_bounds__(256) void k_init_fb(const float* __restrict__ ecfp,
                                                 float* __restrict__ out, int total4) {
    int i = blockIdx.x * 256 + threadIdx.x;
    if (i >= total4) return;
    int row = i / 76, c4 = i - row * 76;
    float4 v = make_float4(0.f, 0.f, 0.f, 0.f);
    if (c4 < 4) v = ((const float4*)ecfp)[row * 4 + c4];
    ((float4*)out)[i] = v;
}

__global__ __launch_bounds__(256) void k_radial_fb(const float* __restrict__ dist,
                                                   const float* __restrict__ sw,
                                                   const int* __restrict__ bond_order,
                                                   const int* __restrict__ esrc,
                                                   const int* __restrict__ edst,
                                                   const int* __restrict__ species,
                                                   float* __restrict__ out, int e_rad) {
    int e = blockIdx.x * 256 + threadIdx.x;
    if (e >= e_rad) return;
    float d = dist[e], s = sw[e];
    int bo = bond_order[e];
    int bb = (bo == 3 || bo == 5) ? 1 : 0;
    int z = species[edst[e]];
    int sp = (z == 6) ? 1 : (z == 7) ? 2 : (z == 8) ? 3 : 0;
    float* base = out + (size_t)esrc[e] * OUTC + 16 + sp * 32 + bb;
    float coef = 0.25f * s;
#pragma unroll
    for (int r = 0; r < 16; ++r) {
        float delta = d - (0.8f + 0.275f * (float)r);
        float v = coef * __expf(-16.0f * delta * delta);
        if (v > 6e-7f) unsafeAtomicAdd(base + r * 2, v);
    }
}

__global__ __launch_bounds__(256) void k_ang_fb(const float* __restrict__ angles,
                                                const float* __restrict__ angd,
                                                const float* __restrict__ angsw,
                                                const int* __restrict__ aedst,
                                                const int* __restrict__ species,
                                                const int* __restrict__ central,
                                                const int* __restrict__ psrc,
                                                const int* __restrict__ pdst,
                                                float* __restrict__ out, int n_pairs) {
    int p = blockIdx.x * 256 + threadIdx.x;
    if (p >= n_pairs) return;
    int is = psrc[p], it = pdst[p];
    float th = angles[p];
    float d12 = 0.5f * (angd[is] + angd[it]);
    float scale = 2.0f * angsw[is] * angsw[it];
    int zs = species[aedst[is]], zt = species[aedst[it]];
    int sps = (zs == 6) ? 1 : (zs == 7) ? 2 : (zs == 8) ? 3 : 0;
    int spt = (zt == 6) ? 1 : (zt == 7) ? 2 : (zt == 8) ? 3 : 0;
    int i = min(sps, spt), j = max(sps, spt);
    int pair = i * 4 - (i * (i - 1)) / 2 + (j - i);
    float sth, cth;
    __sincosf(th, &sth, &cth);
    const float CZ[4] = {0.92387953251f, 0.38268343236f, -0.38268343236f, -0.92387953251f};
    const float SZ[4] = {0.38268343236f, 0.92387953251f, 0.92387953251f, 0.38268343236f};
    float f1[4];
#pragma unroll
    for (int zz = 0; zz < 4; ++zz) {
        float x = 0.5f + 0.5f * (cth * CZ[zz] + sth * SZ[zz]);
        float x2 = x * x, x4 = x2 * x2, x8 = x4 * x4, x16 = x8 * x8;
        f1[zz] = x16 * x16;
    }
    float* base = out + (size_t)central[p] * OUTC + 144 + pair * 16;
#pragma unroll
    for (int a = 0; a < 4; ++a) {
        float da = d12 - (0.8f + 0.675f * (float)a);
        float f2 = __expf(-8.0f * da * da) * scale;
#pragma unroll
        for (int zz = 0; zz < 4; ++zz) {
            float v = f2 * f1[zz];
            if (v > 6e-7f) unsafeAtomicAdd(base + a * 4 + zz, v);
        }
    }
}

extern "C" void kernel_launch(void* const* d_in, const int* in_sizes, int n_in,
                              void* d_out, int out_size, void* d_ws, size_t ws_size,
                              hipStream_t stream) {
    const float* ecfp      = (const float*)d_in[0];
    const float* distances = (const float*)d_in[1];
    const float* sw        = (const float*)d_in[2];
    const float* angles    = (const float*)d_in[3];
    const float* angd      = (const float*)d_in[4];
    const float* angsw     = (const float*)d_in[5];
    const int*   species   = (const int*)d_in[6];
    const int*   bond_ord  = (const int*)d_in[7];
    const int*   edge_src  = (const int*)d_in[8];
    const int*   edge_dst  = (const int*)d_in[9];
    const int*   aedst     = (const int*)d_in[10];
    const int*   central   = (const int*)d_in[11];
    const int*   angle_src = (const int*)d_in[12];
    const int*   angle_dst = (const int*)d_in[13];
    float* out = (float*)d_out;

    const int e_rad   = in_sizes[1];
    const int n_pairs = in_sizes[3];
    const int e_ang   = in_sizes[4];
    const int n_atoms = in_sizes[6];

    const int NB = (n_atoms + 63) / 64;   // 64-atom bins

    size_t pay_bytes  = (size_t)NB * CAP * 8;
    size_t erec_bytes = ((size_t)e_ang * 4 + 15) & ~(size_t)15;
    size_t ovf_bytes  = (size_t)OVF_CAP * 16;
    size_t meta_bytes = (size_t)(2 * NB + 1) * 4;
    size_t need1 = pay_bytes + erec_bytes + ovf_bytes + meta_bytes;
    size_t need2 = 2 * pay_bytes + erec_bytes + ovf_bytes + meta_bytes;

    bool cap_ok = (NB <= NBK) &&
                  (e_rad  <= (size_t)NB * (CAP - 256)) &&
                  (n_pairs <= (size_t)NB * (CAP - 256));

    const int span = SC_F * 2 * 512;   // 16 iterations, 2 flushes per block
    int gridR = (e_rad + span - 1) / span;
    int gridA = (n_pairs + span - 1) / span;
    int total4 = n_atoms * 4;
    int nz = 2 * NB + 1;
    int prepN = max(e_ang, max(total4, nz));

    if (ws_size >= need2 && cap_ok) {
        // ---- fused dual-payload path ----
        uint2*    payR = (uint2*)d_ws;
        uint2*    payA = (uint2*)((char*)d_ws + pay_bytes);
        unsigned* erec = (unsigned*)((char*)d_ws + 2 * pay_bytes);
        uint4*    ovf  = (uint4*)((char*)d_ws + 2 * pay_bytes + erec_bytes);
        int*      gcntR = (int*)((char*)ovf + ovf_bytes);
        int*      gcntA = gcntR + NB;
        int*      ovfc  = gcntA + NB;

        k_prep<<<(prepN + 255) / 256, 256, 0, stream>>>(angd, angsw, aedst, species,
                                                        erec, e_ang, ecfp, out, total4,
                                                        gcntR, nz);
        k_scatter_fused<<<gridR + gridA, 512, 0, stream>>>(
            distances, sw, bond_ord, edge_src, edge_dst, species, gcntR, payR,
            angles, erec, central, angle_src, angle_dst, gcntA, payA,
            ovf, ovfc, e_rad, n_pairs, span, NB, gridR, gridA);
        k_accum_fused<<<2 * NB, 512, 0, stream>>>(payR, gcntR, payA, gcntA, out, n_atoms);
        k_spill<<<16, 256, 0, stream>>>(ovf, ovfc, out);
    } else if (ws_size >= need1 && cap_ok) {
        // ---- sequential single-payload path (round 11) ----
        uint2*    payload = (uint2*)d_ws;
        unsigned* erec    = (unsigned*)((char*)d_ws + pay_bytes);
        uint4*    ovf     = (uint4*)((char*)d_ws + pay_bytes + erec_bytes);
        int*      gcntR   = (int*)((char*)ovf + ovf_bytes);
        int*      gcntA   = gcntR + NB;
        int*      ovfc    = gcntA + NB;

        k_prep<<<(prepN + 255) / 256, 256, 0, stream>>>(angd, angsw, aedst, species,
                                                        erec, e_ang, ecfp, out, total4,
                                                        gcntR, nz);
        k_scatter_rad<<<gridR, 512, 0, stream>>>(distances, sw, bond_ord, edge_src,
                                                 edge_dst, species, gcntR, payload,
                                                 ovf, ovfc, e_rad, span, NB);
        k_accum_rad<<<NB, 512, 0, stream>>>(payload, gcntR, out, n_atoms);
        k_scatter_ang<<<gridA, 512, 0, stream>>>(angles, erec, central, angle_src,
                                                 angle_dst, gcntA, payload,
                                                 ovf, ovfc, n_pairs, span, NB);
        k_accum_ang<<<NB, 512, 0, stream>>>(payload, gcntA, out, n_atoms);
        k_spill<<<16, 256, 0, stream>>>(ovf, ovfc, out);
    } else {
        int t4 = n_atoms * (OUTC / 4);
        k_init_fb<<<(t4 + 255) / 256, 256, 0, stream>>>(ecfp, out, t4);
        k_radial_fb<<<(e_rad + 255) / 256, 256, 0, stream>>>(distances, sw, bond_ord,
                                                             edge_src, edge_dst, species,
                                                             out, e_rad);
        k_ang_fb<<<(n_pairs + 255) / 256, 256, 0, stream>>>(angles, angd, angsw, aedst,
                                                            species, central, angle_src,
                                                            angle_dst, out, n_pairs);
    }
}

// Round 13
// 177.859 us; speedup vs baseline: 1.4537x; 1.0048x over previous
//
#include <hip/hip_runtime.h>
#include <math.h>

#define OUTC 304
#define NBK  784         // max 64-atom bins (>= ceil(50000/64)=782)
#define CAP  3072        // payload slots per bin (lambda ~2558 at 2M items)
#define SC_K 12          // LDS staging depth per bucket
#define SC_F 4           // flush every SC_F iterations of 1024 items (lambda ~5.2)
#define OVF_CAP 65536

// ---------------- fused prep: zero counters + ecfp copy + angular edge records ----------------
__global__ __launch_bounds__(256) void k_prep(const float* __restrict__ angd,
                                              const float* __restrict__ angsw,
                                              const int* __restrict__ aedst,
                                              const int* __restrict__ species,
                                              unsigned* __restrict__ erec, int e_ang,
                                              const float* __restrict__ ecfp,
                                              float* __restrict__ out, int total4,
                                              int* __restrict__ gcnt, int nz) {
    int i = blockIdx.x * 256 + threadIdx.x;
    if (i < nz) gcnt[i] = 0;
    if (i < total4) {
        int row = i >> 2, c4 = i & 3;
        ((float4*)out)[row * (OUTC / 4) + c4] = ((const float4*)ecfp)[i];
    }
    if (i < e_ang) {
        int z = species[aedst[i]];
        unsigned sp = (z == 6) ? 1u : (z == 7) ? 2u : (z == 8) ? 3u : 0u;
        float d = angd[i], s = angsw[i];
        unsigned dq = (unsigned)fminf(fmaxf((d - 0.8f) * (4095.0f / 2.7f) + 0.5f, 0.f), 4095.f);
        unsigned sq = (unsigned)fminf(fmaxf(s * 16383.0f + 0.5f, 0.f), 16383.f);
        erec[i] = dq | (sq << 12) | (sp << 26);
    }
}

// ---------------- shared flush (owner-computes) ----------------
__device__ __forceinline__ void flush_buckets(int* lcnt, uint2* stg,
                                              int* __restrict__ gcnt,
                                              uint2* __restrict__ payload,
                                              uint4* __restrict__ ovf,
                                              int* __restrict__ ovfc,
                                              int nb, unsigned tag) {
    const int tid = threadIdx.x;
    __syncthreads();
#pragma unroll
    for (int q = 0; q < 2; ++q) {
        int b = 2 * tid + q;
        if (b < nb) {
            int c = min(lcnt[b], SC_K);
            if (c > 0) {
                int gbase = atomicAdd(&gcnt[b], c);
                const uint2* sp2 = &stg[b * SC_K];
                uint2* pp = payload + (size_t)b * CAP;
                for (int k = 0; k < c; ++k) {
                    int gpos = gbase + k;
                    uint2 pl = sp2[k];
                    if (gpos < CAP) pp[gpos] = pl;
                    else {
                        int oi = atomicAdd(ovfc, 1);
                        unsigned loc = tag ? ((pl.y >> 16) & 63u) : (pl.y & 63u);
                        if (oi < OVF_CAP) ovf[oi] = make_uint4(pl.x, pl.y, (unsigned)(b * 64 + loc), tag);
                    }
                }
            }
            lcnt[b] = 0;
        }
    }
    __syncthreads();
}

// ================= scatter device bodies (ILP-2, owner-computes flush) =================
__device__ __forceinline__ void scatter_rad_dev(
        const float* __restrict__ dist, const float* __restrict__ sw,
        const int* __restrict__ bond_order, const int* __restrict__ esrc,
        const int* __restrict__ edst, const int* __restrict__ species,
        int* __restrict__ gcnt, uint2* __restrict__ payload,
        uint4* __restrict__ ovf, int* __restrict__ ovfc,
        int n, int span, int nb, int bid, uint2* stg, int* lcnt) {
    const int tid = threadIdx.x;
    for (int i = tid; i < nb; i += 512) lcnt[i] = 0;
    __syncthreads();
    int base = bid * span, end = min(base + span, n);
    if (base >= end) return;
    int pend = 0;
    for (int i0 = base; i0 < end; i0 += 1024) {
        int e0 = i0 + tid, e1 = i0 + 512 + tid;
        bool v0 = e0 < end, v1 = e1 < end;
        // --- issue all independent loads first (MLP) ---
        float d0 = 0.f, s0 = 0.f, d1 = 0.f, s1 = 0.f;
        int bo0 = 0, bo1 = 0, ed0 = 0, ed1 = 0, c0i = 0, c1i = 0;
        if (v0) { d0 = dist[e0]; s0 = sw[e0]; bo0 = bond_order[e0]; c0i = esrc[e0]; ed0 = edst[e0]; }
        if (v1) { d1 = dist[e1]; s1 = sw[e1]; bo1 = bond_order[e1]; c1i = esrc[e1]; ed1 = edst[e1]; }
        int z0 = 0, z1 = 0;
        if (v0) z0 = species[ed0];
        if (v1) z1 = species[ed1];
        if (v0) {
            unsigned bb = (bo0 == 3 || bo0 == 5) ? 1u : 0u;
            unsigned sp = (z0 == 6) ? 1u : (z0 == 7) ? 2u : (z0 == 8) ? 3u : 0u;
            unsigned dq = (unsigned)fminf(fmaxf((d0 - 0.8f) * (65535.0f / 4.4f) + 0.5f, 0.f), 65535.f);
            unsigned sq = (unsigned)fminf(fmaxf(s0 * 65535.0f + 0.5f, 0.f), 65535.f);
            uint2 pl; pl.x = dq | (sq << 16); pl.y = (unsigned)(c0i & 63) | (sp << 6) | (bb << 8);
            int b = c0i >> 6;
            int slot = atomicAdd(&lcnt[b], 1);
            if (slot < SC_K) stg[b * SC_K + slot] = pl;
            else { int oi = atomicAdd(ovfc, 1); if (oi < OVF_CAP) ovf[oi] = make_uint4(pl.x, pl.y, (unsigned)c0i, 0u); }
        }
        if (v1) {
            unsigned bb = (bo1 == 3 || bo1 == 5) ? 1u : 0u;
            unsigned sp = (z1 == 6) ? 1u : (z1 == 7) ? 2u : (z1 == 8) ? 3u : 0u;
            unsigned dq = (unsigned)fminf(fmaxf((d1 - 0.8f) * (65535.0f / 4.4f) + 0.5f, 0.f), 65535.f);
            unsigned sq = (unsigned)fminf(fmaxf(s1 * 65535.0f + 0.5f, 0.f), 65535.f);
            uint2 pl; pl.x = dq | (sq << 16); pl.y = (unsigned)(c1i & 63) | (sp << 6) | (bb << 8);
            int b = c1i >> 6;
            int slot = atomicAdd(&lcnt[b], 1);
            if (slot < SC_K) stg[b * SC_K + slot] = pl;
            else { int oi = atomicAdd(ovfc, 1); if (oi < OVF_CAP) ovf[oi] = make_uint4(pl.x, pl.y, (unsigned)c1i, 0u); }
        }
        if (++pend == SC_F || i0 + 1024 >= end)
            { pend = 0; flush_buckets(lcnt, stg, gcnt, payload, ovf, ovfc, nb, 0u); }
    }
}

__device__ __forceinline__ void scatter_ang_dev(
        const float* __restrict__ angles, const unsigned* __restrict__ erec,
        const int* __restrict__ central, const int* __restrict__ psrc,
        const int* __restrict__ pdst,
        int* __restrict__ gcnt, uint2* __restrict__ payload,
        uint4* __restrict__ ovf, int* __restrict__ ovfc,
        int n, int span, int nb, int bid, uint2* stg, int* lcnt) {
    const int tid = threadIdx.x;
    for (int i = tid; i < nb; i += 512) lcnt[i] = 0;
    __syncthreads();
    int base = bid * span, end = min(base + span, n);
    if (base >= end) return;
    int pend = 0;
    for (int i0 = base; i0 < end; i0 += 1024) {
        int p0 = i0 + tid, p1 = i0 + 512 + tid;
        bool v0 = p0 < end, v1 = p1 < end;
        // --- issue all independent loads first (MLP): indices then 4 gathers ---
        int is0 = 0, it0 = 0, is1 = 0, it1 = 0, c0i = 0, c1i = 0;
        float th0 = 0.f, th1 = 0.f;
        if (v0) { is0 = psrc[p0]; it0 = pdst[p0]; c0i = central[p0]; th0 = angles[p0]; }
        if (v1) { is1 = psrc[p1]; it1 = pdst[p1]; c1i = central[p1]; th1 = angles[p1]; }
        unsigned rs0 = 0, rt0 = 0, rs1 = 0, rt1 = 0;
        if (v0) { rs0 = erec[is0]; rt0 = erec[it0]; }
        if (v1) { rs1 = erec[is1]; rt1 = erec[it1]; }
        if (v0) {
            float dsrc = 0.8f + (float)(rs0 & 0xfffu) * (2.7f / 4095.0f);
            float dtgt = 0.8f + (float)(rt0 & 0xfffu) * (2.7f / 4095.0f);
            float ss = (float)((rs0 >> 12) & 0x3fffu) * (1.0f / 16383.0f);
            float st = (float)((rt0 >> 12) & 0x3fffu) * (1.0f / 16383.0f);
            int sps = (int)(rs0 >> 26), spt = (int)(rt0 >> 26);
            int i = min(sps, spt), j = max(sps, spt);
            unsigned pair = (unsigned)(i * 4 - (i * (i - 1)) / 2 + (j - i));
            float d12 = 0.5f * (dsrc + dtgt);
            float scale = 2.0f * ss * st;
            unsigned tq = (unsigned)fminf(fmaxf(th0 * (65535.0f / 3.14159265358979f) + 0.5f, 0.f), 65535.f);
            unsigned dq = (unsigned)fminf(fmaxf((d12 - 0.8f) * (65535.0f / 2.7f) + 0.5f, 0.f), 65535.f);
            unsigned sq = (unsigned)fminf(fmaxf(scale * (65535.0f / 2.0f) + 0.5f, 0.f), 65535.f);
            uint2 pl; pl.x = tq | (dq << 16); pl.y = sq | ((unsigned)(c0i & 63) << 16) | (pair << 22);
            int b = c0i >> 6;
            int slot = atomicAdd(&lcnt[b], 1);
            if (slot < SC_K) stg[b * SC_K + slot] = pl;
            else { int oi = atomicAdd(ovfc, 1); if (oi < OVF_CAP) ovf[oi] = make_uint4(pl.x, pl.y, (unsigned)c0i, 1u); }
        }
        if (v1) {
            float dsrc = 0.8f + (float)(rs1 & 0xfffu) * (2.7f / 4095.0f);
            float dtgt = 0.8f + (float)(rt1 & 0xfffu) * (2.7f / 4095.0f);
            float ss = (float)((rs1 >> 12) & 0x3fffu) * (1.0f / 16383.0f);
            float st = (float)((rt1 >> 12) & 0x3fffu) * (1.0f / 16383.0f);
            int sps = (int)(rs1 >> 26), spt = (int)(rt1 >> 26);
            int i = min(sps, spt), j = max(sps, spt);
            unsigned pair = (unsigned)(i * 4 - (i * (i - 1)) / 2 + (j - i));
            float d12 = 0.5f * (dsrc + dtgt);
            float scale = 2.0f * ss * st;
            unsigned tq = (unsigned)fminf(fmaxf(th1 * (65535.0f / 3.14159265358979f) + 0.5f, 0.f), 65535.f);
            unsigned dq = (unsigned)fminf(fmaxf((d12 - 0.8f) * (65535.0f / 2.7f) + 0.5f, 0.f), 65535.f);
            unsigned sq = (unsigned)fminf(fmaxf(scale * (65535.0f / 2.0f) + 0.5f, 0.f), 65535.f);
            uint2 pl; pl.x = tq | (dq << 16); pl.y = sq | ((unsigned)(c1i & 63) << 16) | (pair << 22);
            int b = c1i >> 6;
            int slot = atomicAdd(&lcnt[b], 1);
            if (slot < SC_K) stg[b * SC_K + slot] = pl;
            else { int oi = atomicAdd(ovfc, 1); if (oi < OVF_CAP) ovf[oi] = make_uint4(pl.x, pl.y, (unsigned)c1i, 1u); }
        }
        if (++pend == SC_F || i0 + 1024 >= end)
            { pend = 0; flush_buckets(lcnt, stg, gcnt, payload, ovf, ovfc, nb, 1u); }
    }
}

// ---------------- per-item accumulate helpers: window + per-lane threshold ----------------
#define VTHR 1.5e-3f

__device__ __forceinline__ void proc_rad(uint2 pl, float* acc) {
    float d = 0.8f + (float)(pl.x & 0xffffu) * (4.4f / 65535.0f);
    float coef = 0.25f * (float)(pl.x >> 16) * (1.0f / 65535.0f);
    int bidx = (int)(pl.y & 63u) * 129 + (int)((pl.y >> 6) & 3u) * 32 + (int)((pl.y >> 8) & 1u);
    int c0 = (int)((d - 0.8f) * (1.0f / 0.275f)) - 1;
    c0 = max(0, min(12, c0));
    float dd = d - (0.8f + 0.275f * (float)c0);
    float* ap = acc + bidx + c0 * 2;
#pragma unroll
    for (int kk = 0; kk < 4; ++kk) {
        float delta = dd - 0.275f * (float)kk;
        float v = coef * __expf(-16.0f * delta * delta);
        if (v > VTHR) atomicAdd(&ap[kk * 2], v);
    }
}

__device__ __forceinline__ void proc_ang(uint2 pl, float* acc) {
    float th    = (float)(pl.x & 0xffffu) * (3.14159265358979f / 65535.0f);
    float d12   = 0.8f + (float)(pl.x >> 16) * (2.7f / 65535.0f);
    float scale = (float)(pl.y & 0xffffu) * (2.0f / 65535.0f);
    int rowb = (int)((pl.y >> 16) & 63u) * 161 + (int)((pl.y >> 22) & 15u) * 16;
    int z0 = (int)(th * (4.0f / 3.14159265358979f) - 0.5f);
    z0 = max(0, min(2, z0));
    float cz = (z0 == 0) ? 0.92387953251f : ((z0 == 1) ? 0.38268343236f : -0.38268343236f);
    float sz = (z0 == 0) ? 0.38268343236f : 0.92387953251f;
    float sth, cth;
    __sincosf(th, &sth, &cth);
    float cq = cth * cz + sth * sz;
    float sq = sth * cz - cth * sz;
    float xa = 0.5f + 0.5f * cq;
    float cq1 = 0.70710678119f * (cq + sq);
    float xb = 0.5f + 0.5f * cq1;
    float x2, x4, x8, x16, f1a, f1b;
    x2 = xa * xa; x4 = x2 * x2; x8 = x4 * x4; x16 = x8 * x8; f1a = x16 * x16;
    x2 = xb * xb; x4 = x2 * x2; x8 = x4 * x4; x16 = x8 * x8; f1b = x16 * x16;
    int ar = (int)((d12 - 0.8f) * (1.0f / 0.675f) + 0.5f);
    int a0 = max(0, min(1, ar - 1));
    float da = d12 - (0.8f + 0.675f * (float)a0);
    float* ap = acc + rowb + a0 * 4 + z0;
#pragma unroll
    for (int aa = 0; aa < 3; ++aa) {
        float delta = da - 0.675f * (float)aa;
        float f2 = __expf(-8.0f * delta * delta) * scale;
        float v0 = f2 * f1a;
        float v1 = f2 * f1b;
        if (v0 > VTHR) atomicAdd(&ap[aa * 4], v0);
        if (v1 > VTHR) atomicAdd(&ap[aa * 4 + 1], v1);
    }
}

// ================= accumulate device bodies =================
__device__ __forceinline__ void accum_rad_dev(const uint2* __restrict__ payload,
                                              const int* __restrict__ gcnt,
                                              float* __restrict__ out, int n_atoms,
                                              int b, float* acc) {
    for (int i = threadIdx.x; i < 64 * 129; i += 512) acc[i] = 0.f;
    __syncthreads();
    int len = min(gcnt[b], CAP);
    const uint2* pp = payload + (size_t)b * CAP;
    for (int r = threadIdx.x; r < len; r += 512) proc_rad(pp[r], acc);
    __syncthreads();
    int a0 = b * 64;
    for (int i = threadIdx.x; i < 64 * 128; i += 512) {
        int la = i >> 7, cc = i & 127;
        int atom = a0 + la;
        if (atom < n_atoms) out[(size_t)atom * OUTC + 16 + cc] = acc[la * 129 + cc];
    }
}

__device__ __forceinline__ void accum_ang_dev(const uint2* __restrict__ payload,
                                              const int* __restrict__ gcnt,
                                              float* __restrict__ out, int n_atoms,
                                              int b, float* acc) {
    for (int i = threadIdx.x; i < 64 * 161; i += 512) acc[i] = 0.f;
    __syncthreads();
    int len = min(gcnt[b], CAP);
    const uint2* pp = payload + (size_t)b * CAP;
    for (int r = threadIdx.x; r < len; r += 512) proc_ang(pp[r], acc);
    __syncthreads();
    int a0 = b * 64;
    for (int i = threadIdx.x; i < 64 * 160; i += 512) {
        int la = i / 160, cc = i - la * 160;
        int atom = a0 + la;
        if (atom < n_atoms) out[(size_t)atom * OUTC + 144 + cc] = acc[la * 161 + cc];
    }
}

// ================= fused kernels (dual-payload path) =================
__global__ __launch_bounds__(512) void k_scatter_fused(
        const float* __restrict__ dist, const float* __restrict__ sw,
        const int* __restrict__ bond_order, const int* __restrict__ esrc,
        const int* __restrict__ edst, const int* __restrict__ species,
        int* __restrict__ gcntR, uint2* __restrict__ payR,
        const float* __restrict__ angles, const unsigned* __restrict__ erec,
        const int* __restrict__ central, const int* __restrict__ psrc,
        const int* __restrict__ pdst,
        int* __restrict__ gcntA, uint2* __restrict__ payA,
        uint4* __restrict__ ovf, int* __restrict__ ovfc,
        int e_rad, int n_pairs, int span, int nb, int gridR, int gridA) {
    __shared__ uint2 stg[NBK * SC_K];
    __shared__ int lcnt[NBK];
    int m = min(gridR, gridA), m2 = 2 * m;
    int bi = (int)blockIdx.x;
    bool ang; int bidx;
    if (bi < m2) { ang = bi & 1; bidx = bi >> 1; }
    else { ang = (gridA > gridR); bidx = m + (bi - m2); }
    if (ang)
        scatter_ang_dev(angles, erec, central, psrc, pdst, gcntA, payA,
                        ovf, ovfc, n_pairs, span, nb, bidx, stg, lcnt);
    else
        scatter_rad_dev(dist, sw, bond_order, esrc, edst, species, gcntR, payR,
                        ovf, ovfc, e_rad, span, nb, bidx, stg, lcnt);
}

__global__ __launch_bounds__(512) void k_accum_fused(const uint2* __restrict__ payR,
                                                     const int* __restrict__ gcntR,
                                                     const uint2* __restrict__ payA,
                                                     const int* __restrict__ gcntA,
                                                     float* __restrict__ out, int n_atoms) {
    __shared__ float acc[64 * 161];   // 41 KB frame shared by both types
    int b = blockIdx.x >> 1;
    if (blockIdx.x & 1) accum_ang_dev(payA, gcntA, out, n_atoms, b, acc);
    else                accum_rad_dev(payR, gcntR, out, n_atoms, b, acc);
}

// ================= sequential-path thin kernels (single payload) =================
__global__ __launch_bounds__(512) void k_scatter_rad(
        const float* __restrict__ dist, const float* __restrict__ sw,
        const int* __restrict__ bond_order, const int* __restrict__ esrc,
        const int* __restrict__ edst, const int* __restrict__ species,
        int* __restrict__ gcnt, uint2* __restrict__ payload,
        uint4* __restrict__ ovf, int* __restrict__ ovfc,
        int n, int span, int nb) {
    __shared__ uint2 stg[NBK * SC_K];
    __shared__ int lcnt[NBK];
    scatter_rad_dev(dist, sw, bond_order, esrc, edst, species, gcnt, payload,
                    ovf, ovfc, n, span, nb, blockIdx.x, stg, lcnt);
}

__global__ __launch_bounds__(512) void k_scatter_ang(
        const float* __restrict__ angles, const unsigned* __restrict__ erec,
        const int* __restrict__ central, const int* __restrict__ psrc,
        const int* __restrict__ pdst,
        int* __restrict__ gcnt, uint2* __restrict__ payload,
        uint4* __restrict__ ovf, int* __restrict__ ovfc,
        int n, int span, int nb) {
    __shared__ uint2 stg[NBK * SC_K];
    __shared__ int lcnt[NBK];
    scatter_ang_dev(angles, erec, central, psrc, pdst, gcnt, payload,
                    ovf, ovfc, n, span, nb, blockIdx.x, stg, lcnt);
}

__global__ __launch_bounds__(512) void k_accum_rad(const uint2* __restrict__ payload,
                                                   const int* __restrict__ gcnt,
                                                   float* __restrict__ out, int n_atoms) {
    __shared__ float acc[64 * 129];
    accum_rad_dev(payload, gcnt, out, n_atoms, blockIdx.x, acc);
}

__global__ __launch_bounds__(512) void k_accum_ang(const uint2* __restrict__ payload,
                                                   const int* __restrict__ gcnt,
                                                   float* __restrict__ out, int n_atoms) {
    __shared__ float acc[64 * 161];
    accum_ang_dev(payload, gcnt, out, n_atoms, blockIdx.x, acc);
}

// ---------------- overflow spill (rare; exact full window) ----------------
__global__ __launch_bounds__(256) void k_spill(const uint4* __restrict__ ovf,
                                               const int* __restrict__ ovfc,
                                               float* __restrict__ out) {
    int n = min(*ovfc, OVF_CAP);
    const float CZ[4] = {0.92387953251f, 0.38268343236f, -0.38268343236f, -0.92387953251f};
    const float SZ[4] = {0.38268343236f, 0.92387953251f, 0.92387953251f, 0.38268343236f};
    for (int idx = blockIdx.x * 256 + threadIdx.x; idx < n; idx += gridDim.x * 256) {
        uint4 e = ovf[idx];
        if (e.w == 0u) {   // radial
            float d = 0.8f + (float)(e.x & 0xffffu) * (4.4f / 65535.0f);
            float coef = 0.25f * (float)(e.x >> 16) * (1.0f / 65535.0f);
            int sp = (int)((e.y >> 6) & 3u), bb = (int)((e.y >> 8) & 1u);
            float* base = out + (size_t)e.z * OUTC + 16 + sp * 32 + bb;
            for (int k = 0; k < 16; ++k) {
                float delta = d - (0.8f + 0.275f * (float)k);
                float v = coef * __expf(-16.0f * delta * delta);
                if (v > 1e-6f) unsafeAtomicAdd(base + k * 2, v);
            }
        } else {           // angular
            float th    = (float)(e.x & 0xffffu) * (3.14159265358979f / 65535.0f);
            float d12   = 0.8f + (float)(e.x >> 16) * (2.7f / 65535.0f);
            float scale = (float)(e.y & 0xffffu) * (2.0f / 65535.0f);
            int pair = (int)((e.y >> 22) & 15u);
            float* base = out + (size_t)e.z * OUTC + 144 + pair * 16;
            float sth, cth;
            __sincosf(th, &sth, &cth);
            for (int zz = 0; zz < 4; ++zz) {
                float x = 0.5f + 0.5f * (cth * CZ[zz] + sth * SZ[zz]);
                float x2 = x * x, x4 = x2 * x2, x8 = x4 * x4, x16 = x8 * x8;
                float f1 = x16 * x16;
                for (int a = 0; a < 4; ++a) {
                    float da = d12 - (0.8f + 0.675f * (float)a);
                    float v = __expf(-8.0f * da * da) * scale * f1;
                    if (v > 1e-6f) unsafeAtomicAdd(base + a * 4 + zz, v);
                }
            }
        }
    }
}

// ================= fallback (round-1 atomic path) =================
__global__ __launch_bounds__(256) void k_init_fb(const float* __restrict__ ecfp,
                                                 float* __restrict__ out, int total4) {
    int i = blockIdx.x * 256 + threadIdx.x;
    if (i >= total4) return;
    int row = i / 76, c4 = i - row * 76;
    float4 v = make_float4(0.f, 0.f, 0.f, 0.f);
    if (c4 < 4) v = ((const float4*)ecfp)[row * 4 + c4];
    ((float4*)out)[i] = v;
}

__global__ __launch_bounds__(256) void k_radial_fb(const float* __restrict__ dist,
                                                   const float* __restrict__ sw,
                                                   const int* __restrict__ bond_order,
                                                   const int* __restrict__ esrc,
                                                   const int* __restrict__ edst,
                                                   const int* __restrict__ species,
                                                   float* __restrict__ out, int e_rad) {
    int e = blockIdx.x * 256 + threadIdx.x;
    if (e >= e_rad) return;
    float d = dist[e], s = sw[e];
    int bo = bond_order[e];
    int bb = (bo == 3 || bo == 5) ? 1 : 0;
    int z = species[edst[e]];
    int sp = (z == 6) ? 1 : (z == 7) ? 2 : (z == 8) ? 3 : 0;
    float* base = out + (size_t)esrc[e] * OUTC + 16 + sp * 32 + bb;
    float coef = 0.25f * s;
#pragma unroll
    for (int r = 0; r < 16; ++r) {
        float delta = d - (0.8f + 0.275f * (float)r);
        float v = coef * __expf(-16.0f * delta * delta);
        if (v > 6e-7f) unsafeAtomicAdd(base + r * 2, v);
    }
}

__global__ __launch_bounds__(256) void k_ang_fb(const float* __restrict__ angles,
                                                const float* __restrict__ angd,
                                                const float* __restrict__ angsw,
                                                const int* __restrict__ aedst,
                                                const int* __restrict__ species,
                                                const int* __restrict__ central,
                                                const int* __restrict__ psrc,
                                                const int* __restrict__ pdst,
                                                float* __restrict__ out, int n_pairs) {
    int p = blockIdx.x * 256 + threadIdx.x;
    if (p >= n_pairs) return;
    int is = psrc[p], it = pdst[p];
    float th = angles[p];
    float d12 = 0.5f * (angd[is] + angd[it]);
    float scale = 2.0f * angsw[is] * angsw[it];
    int zs = species[aedst[is]], zt = species[aedst[it]];
    int sps = (zs == 6) ? 1 : (zs == 7) ? 2 : (zs == 8) ? 3 : 0;
    int spt = (zt == 6) ? 1 : (zt == 7) ? 2 : (zt == 8) ? 3 : 0;
    int i = min(sps, spt), j = max(sps, spt);
    int pair = i * 4 - (i * (i - 1)) / 2 + (j - i);
    float sth, cth;
    __sincosf(th, &sth, &cth);
    const float CZ[4] = {0.92387953251f, 0.38268343236f, -0.38268343236f, -0.92387953251f};
    const float SZ[4] = {0.38268343236f, 0.92387953251f, 0.92387953251f, 0.38268343236f};
    float f1[4];
#pragma unroll
    for (int zz = 0; zz < 4; ++zz) {
        float x = 0.5f + 0.5f * (cth * CZ[zz] + sth * SZ[zz]);
        float x2 = x * x, x4 = x2 * x2, x8 = x4 * x4, x16 = x8 * x8;
        f1[zz] = x16 * x16;
    }
    float* base = out + (size_t)central[p] * OUTC + 144 + pair * 16;
#pragma unroll
    for (int a = 0; a < 4; ++a) {
        float da = d12 - (0.8f + 0.675f * (float)a);
        float f2 = __expf(-8.0f * da * da) * scale;
#pragma unroll
        for (int zz = 0; zz < 4; ++zz) {
            float v = f2 * f1[zz];
            if (v > 6e-7f) unsafeAtomicAdd(base + a * 4 + zz, v);
        }
    }
}

extern "C" void kernel_launch(void* const* d_in, const int* in_sizes, int n_in,
                              void* d_out, int out_size, void* d_ws, size_t ws_size,
                              hipStream_t stream) {
    const float* ecfp      = (const float*)d_in[0];
    const float* distances = (const float*)d_in[1];
    const float* sw        = (const float*)d_in[2];
    const float* angles    = (const float*)d_in[3];
    const float* angd      = (const float*)d_in[4];
    const float* angsw     = (const float*)d_in[5];
    const int*   species   = (const int*)d_in[6];
    const int*   bond_ord  = (const int*)d_in[7];
    const int*   edge_src  = (const int*)d_in[8];
    const int*   edge_dst  = (const int*)d_in[9];
    const int*   aedst     = (const int*)d_in[10];
    const int*   central   = (const int*)d_in[11];
    const int*   angle_src = (const int*)d_in[12];
    const int*   angle_dst = (const int*)d_in[13];
    float* out = (float*)d_out;

    const int e_rad   = in_sizes[1];
    const int n_pairs = in_sizes[3];
    const int e_ang   = in_sizes[4];
    const int n_atoms = in_sizes[6];

    const int NB = (n_atoms + 63) / 64;   // 64-atom bins

    size_t pay_bytes  = (size_t)NB * CAP * 8;
    size_t erec_bytes = ((size_t)e_ang * 4 + 15) & ~(size_t)15;
    size_t ovf_bytes  = (size_t)OVF_CAP * 16;
    size_t meta_bytes = (size_t)(2 * NB + 1) * 4;
    size_t need1 = pay_bytes + erec_bytes + ovf_bytes + meta_bytes;
    size_t need2 = 2 * pay_bytes + erec_bytes + ovf_bytes + meta_bytes;

    bool cap_ok = (NB <= NBK) &&
                  (e_rad  <= (size_t)NB * (CAP - 256)) &&
                  (n_pairs <= (size_t)NB * (CAP - 256));

    const int span = SC_F * 2 * 1024;   // 8 ILP-2 iterations, 2 flushes per block
    int gridR = (e_rad + span - 1) / span;
    int gridA = (n_pairs + span - 1) / span;
    int total4 = n_atoms * 4;
    int nz = 2 * NB + 1;
    int prepN = max(e_ang, max(total4, nz));

    if (ws_size >= need2 && cap_ok) {
        // ---- fused dual-payload path ----
        uint2*    payR = (uint2*)d_ws;
        uint2*    payA = (uint2*)((char*)d_ws + pay_bytes);
        unsigned* erec = (unsigned*)((char*)d_ws + 2 * pay_bytes);
        uint4*    ovf  = (uint4*)((char*)d_ws + 2 * pay_bytes + erec_bytes);
        int*      gcntR = (int*)((char*)ovf + ovf_bytes);
        int*      gcntA = gcntR + NB;
        int*      ovfc  = gcntA + NB;

        k_prep<<<(prepN + 255) / 256, 256, 0, stream>>>(angd, angsw, aedst, species,
                                                        erec, e_ang, ecfp, out, total4,
                                                        gcntR, nz);
        k_scatter_fused<<<gridR + gridA, 512, 0, stream>>>(
            distances, sw, bond_ord, edge_src, edge_dst, species, gcntR, payR,
            angles, erec, central, angle_src, angle_dst, gcntA, payA,
            ovf, ovfc, e_rad, n_pairs, span, NB, gridR, gridA);
        k_accum_fused<<<2 * NB, 512, 0, stream>>>(payR, gcntR, payA, gcntA, out, n_atoms);
        k_spill<<<16, 256, 0, stream>>>(ovf, ovfc, out);
    } else if (ws_size >= need1 && cap_ok) {
        // ---- sequential single-payload path ----
        uint2*    payload = (uint2*)d_ws;
        unsigned* erec    = (unsigned*)((char*)d_ws + pay_bytes);
        uint4*    ovf     = (uint4*)((char*)d_ws + pay_bytes + erec_bytes);
        int*      gcntR   = (int*)((char*)ovf + ovf_bytes);
        int*      gcntA   = gcntR + NB;
        int*      ovfc    = gcntA + NB;

        k_prep<<<(prepN + 255) / 256, 256, 0, stream>>>(angd, angsw, aedst, species,
                                                        erec, e_ang, ecfp, out, total4,
                                                        gcntR, nz);
        k_scatter_rad<<<gridR, 512, 0, stream>>>(distances, sw, bond_ord, edge_src,
                                                 edge_dst, species, gcntR, payload,
                                                 ovf, ovfc, e_rad, span, NB);
        k_accum_rad<<<NB, 512, 0, stream>>>(payload, gcntR, out, n_atoms);
        k_scatter_ang<<<gridA, 512, 0, stream>>>(angles, erec, central, angle_src,
                                                 angle_dst, gcntA, payload,
                                                 ovf, ovfc, n_pairs, span, NB);
        k_accum_ang<<<NB, 512, 0, stream>>>(payload, gcntA, out, n_atoms);
        k_spill<<<16, 256, 0, stream>>>(ovf, ovfc, out);
    } else {
        int t4 = n_atoms * (OUTC / 4);
        k_init_fb<<<(t4 + 255) / 256, 256, 0, stream>>>(ecfp, out, t4);
        k_radial_fb<<<(e_rad + 255) / 256, 256, 0, stream>>>(distances, sw, bond_ord,
                                                             edge_src, edge_dst, species,
                                                             out, e_rad);
        k_ang_fb<<<(n_pairs + 255) / 256, 256, 0, stream>>>(angles, angd, angsw, aedst,
                                                            species, central, angle_src,
                                                            angle_dst, out, n_pairs);
    }
}

// Round 14
// 173.066 us; speedup vs baseline: 1.4939x; 1.0277x over previous
//
#include <hip/hip_runtime.h>
#include <math.h>

#define OUTC 304
#define NBK  400         // max 128-atom bins (>= ceil(50000/128)=391)
#define CAP  6144        // payload slots per bin (lambda ~5115 at 2M items)
#define SC_K 22          // LDS staging depth per bucket (lambda/flush ~10.5)
#define SC_F 4           // flush every SC_F ILP-2 iterations (4096 items)
#define OVF_CAP 65536

// ---------------- fused prep: zero counters + ecfp copy + angular edge records ----------------
__global__ __launch_bounds__(256) void k_prep(const float* __restrict__ angd,
                                              const float* __restrict__ angsw,
                                              const int* __restrict__ aedst,
                                              const int* __restrict__ species,
                                              unsigned* __restrict__ erec, int e_ang,
                                              const float* __restrict__ ecfp,
                                              float* __restrict__ out, int total4,
                                              int* __restrict__ gcnt, int nz) {
    int i = blockIdx.x * 256 + threadIdx.x;
    if (i < nz) gcnt[i] = 0;
    if (i < total4) {
        int row = i >> 2, c4 = i & 3;
        ((float4*)out)[row * (OUTC / 4) + c4] = ((const float4*)ecfp)[i];
    }
    if (i < e_ang) {
        int z = species[aedst[i]];
        unsigned sp = (z == 6) ? 1u : (z == 7) ? 2u : (z == 8) ? 3u : 0u;
        float d = angd[i], s = angsw[i];
        unsigned dq = (unsigned)fminf(fmaxf((d - 0.8f) * (4095.0f / 2.7f) + 0.5f, 0.f), 4095.f);
        unsigned sq = (unsigned)fminf(fmaxf(s * 16383.0f + 0.5f, 0.f), 16383.f);
        erec[i] = dq | (sq << 12) | (sp << 26);
    }
}

// ---------------- shared flush: one bucket per thread, burst drain ----------------
__device__ __forceinline__ void flush_buckets(int* lcnt, uint2* stg,
                                              int* __restrict__ gcnt,
                                              uint2* __restrict__ payload,
                                              uint4* __restrict__ ovf,
                                              int* __restrict__ ovfc,
                                              int nb, unsigned tag) {
    const int b = threadIdx.x;
    __syncthreads();
    if (b < nb) {
        int c = min(lcnt[b], SC_K);
        if (c > 0) {
            int gbase = atomicAdd(&gcnt[b], c);
            const uint2* sp2 = &stg[b * SC_K];
            uint2* pp = payload + (size_t)b * CAP;
            for (int k = 0; k < c; ++k) {
                int gpos = gbase + k;
                uint2 pl = sp2[k];
                if (gpos < CAP) pp[gpos] = pl;
                else {
                    int oi = atomicAdd(ovfc, 1);
                    unsigned loc = tag ? ((pl.y >> 16) & 127u) : (pl.y & 127u);
                    if (oi < OVF_CAP) ovf[oi] = make_uint4(pl.x, pl.y, (unsigned)(b * 128 + loc), tag);
                }
            }
        }
        lcnt[b] = 0;
    }
    __syncthreads();
}

// ================= scatter device bodies (ILP-2, 128-atom buckets) =================
// radial payload: x = dq16|sq16 ; y = loc7 | sp2<<7 | bb1<<9
__device__ __forceinline__ void scatter_rad_dev(
        const float* __restrict__ dist, const float* __restrict__ sw,
        const int* __restrict__ bond_order, const int* __restrict__ esrc,
        const int* __restrict__ edst, const int* __restrict__ species,
        int* __restrict__ gcnt, uint2* __restrict__ payload,
        uint4* __restrict__ ovf, int* __restrict__ ovfc,
        int n, int span, int nb, int bid, uint2* stg, int* lcnt) {
    const int tid = threadIdx.x;
    for (int i = tid; i < nb; i += 512) lcnt[i] = 0;
    __syncthreads();
    int base = bid * span, end = min(base + span, n);
    if (base >= end) return;
    int pend = 0;
    for (int i0 = base; i0 < end; i0 += 1024) {
        int e0 = i0 + tid, e1 = i0 + 512 + tid;
        bool v0 = e0 < end, v1 = e1 < end;
        float d0 = 0.f, s0 = 0.f, d1 = 0.f, s1 = 0.f;
        int bo0 = 0, bo1 = 0, ed0 = 0, ed1 = 0, c0i = 0, c1i = 0;
        if (v0) { d0 = dist[e0]; s0 = sw[e0]; bo0 = bond_order[e0]; c0i = esrc[e0]; ed0 = edst[e0]; }
        if (v1) { d1 = dist[e1]; s1 = sw[e1]; bo1 = bond_order[e1]; c1i = esrc[e1]; ed1 = edst[e1]; }
        int z0 = 0, z1 = 0;
        if (v0) z0 = species[ed0];
        if (v1) z1 = species[ed1];
        if (v0) {
            unsigned bb = (bo0 == 3 || bo0 == 5) ? 1u : 0u;
            unsigned sp = (z0 == 6) ? 1u : (z0 == 7) ? 2u : (z0 == 8) ? 3u : 0u;
            unsigned dq = (unsigned)fminf(fmaxf((d0 - 0.8f) * (65535.0f / 4.4f) + 0.5f, 0.f), 65535.f);
            unsigned sq = (unsigned)fminf(fmaxf(s0 * 65535.0f + 0.5f, 0.f), 65535.f);
            uint2 pl; pl.x = dq | (sq << 16); pl.y = (unsigned)(c0i & 127) | (sp << 7) | (bb << 9);
            int b = c0i >> 7;
            int slot = atomicAdd(&lcnt[b], 1);
            if (slot < SC_K) stg[b * SC_K + slot] = pl;
            else { int oi = atomicAdd(ovfc, 1); if (oi < OVF_CAP) ovf[oi] = make_uint4(pl.x, pl.y, (unsigned)c0i, 0u); }
        }
        if (v1) {
            unsigned bb = (bo1 == 3 || bo1 == 5) ? 1u : 0u;
            unsigned sp = (z1 == 6) ? 1u : (z1 == 7) ? 2u : (z1 == 8) ? 3u : 0u;
            unsigned dq = (unsigned)fminf(fmaxf((d1 - 0.8f) * (65535.0f / 4.4f) + 0.5f, 0.f), 65535.f);
            unsigned sq = (unsigned)fminf(fmaxf(s1 * 65535.0f + 0.5f, 0.f), 65535.f);
            uint2 pl; pl.x = dq | (sq << 16); pl.y = (unsigned)(c1i & 127) | (sp << 7) | (bb << 9);
            int b = c1i >> 7;
            int slot = atomicAdd(&lcnt[b], 1);
            if (slot < SC_K) stg[b * SC_K + slot] = pl;
            else { int oi = atomicAdd(ovfc, 1); if (oi < OVF_CAP) ovf[oi] = make_uint4(pl.x, pl.y, (unsigned)c1i, 0u); }
        }
        if (++pend == SC_F || i0 + 1024 >= end)
            { pend = 0; flush_buckets(lcnt, stg, gcnt, payload, ovf, ovfc, nb, 0u); }
    }
}

// angular payload: x = tq16|dq16 ; y = sq16 | loc7<<16 | pair4<<23
__device__ __forceinline__ void scatter_ang_dev(
        const float* __restrict__ angles, const unsigned* __restrict__ erec,
        const int* __restrict__ central, const int* __restrict__ psrc,
        const int* __restrict__ pdst,
        int* __restrict__ gcnt, uint2* __restrict__ payload,
        uint4* __restrict__ ovf, int* __restrict__ ovfc,
        int n, int span, int nb, int bid, uint2* stg, int* lcnt) {
    const int tid = threadIdx.x;
    for (int i = tid; i < nb; i += 512) lcnt[i] = 0;
    __syncthreads();
    int base = bid * span, end = min(base + span, n);
    if (base >= end) return;
    int pend = 0;
    for (int i0 = base; i0 < end; i0 += 1024) {
        int p0 = i0 + tid, p1 = i0 + 512 + tid;
        bool v0 = p0 < end, v1 = p1 < end;
        int is0 = 0, it0 = 0, is1 = 0, it1 = 0, c0i = 0, c1i = 0;
        float th0 = 0.f, th1 = 0.f;
        if (v0) { is0 = psrc[p0]; it0 = pdst[p0]; c0i = central[p0]; th0 = angles[p0]; }
        if (v1) { is1 = psrc[p1]; it1 = pdst[p1]; c1i = central[p1]; th1 = angles[p1]; }
        unsigned rs0 = 0, rt0 = 0, rs1 = 0, rt1 = 0;
        if (v0) { rs0 = erec[is0]; rt0 = erec[it0]; }
        if (v1) { rs1 = erec[is1]; rt1 = erec[it1]; }
        if (v0) {
            float dsrc = 0.8f + (float)(rs0 & 0xfffu) * (2.7f / 4095.0f);
            float dtgt = 0.8f + (float)(rt0 & 0xfffu) * (2.7f / 4095.0f);
            float ss = (float)((rs0 >> 12) & 0x3fffu) * (1.0f / 16383.0f);
            float st = (float)((rt0 >> 12) & 0x3fffu) * (1.0f / 16383.0f);
            int sps = (int)(rs0 >> 26), spt = (int)(rt0 >> 26);
            int i = min(sps, spt), j = max(sps, spt);
            unsigned pair = (unsigned)(i * 4 - (i * (i - 1)) / 2 + (j - i));
            float d12 = 0.5f * (dsrc + dtgt);
            float scale = 2.0f * ss * st;
            unsigned tq = (unsigned)fminf(fmaxf(th0 * (65535.0f / 3.14159265358979f) + 0.5f, 0.f), 65535.f);
            unsigned dq = (unsigned)fminf(fmaxf((d12 - 0.8f) * (65535.0f / 2.7f) + 0.5f, 0.f), 65535.f);
            unsigned sq = (unsigned)fminf(fmaxf(scale * (65535.0f / 2.0f) + 0.5f, 0.f), 65535.f);
            uint2 pl; pl.x = tq | (dq << 16); pl.y = sq | ((unsigned)(c0i & 127) << 16) | (pair << 23);
            int b = c0i >> 7;
            int slot = atomicAdd(&lcnt[b], 1);
            if (slot < SC_K) stg[b * SC_K + slot] = pl;
            else { int oi = atomicAdd(ovfc, 1); if (oi < OVF_CAP) ovf[oi] = make_uint4(pl.x, pl.y, (unsigned)c0i, 1u); }
        }
        if (v1) {
            float dsrc = 0.8f + (float)(rs1 & 0xfffu) * (2.7f / 4095.0f);
            float dtgt = 0.8f + (float)(rt1 & 0xfffu) * (2.7f / 4095.0f);
            float ss = (float)((rs1 >> 12) & 0x3fffu) * (1.0f / 16383.0f);
            float st = (float)((rt1 >> 12) & 0x3fffu) * (1.0f / 16383.0f);
            int sps = (int)(rs1 >> 26), spt = (int)(rt1 >> 26);
            int i = min(sps, spt), j = max(sps, spt);
            unsigned pair = (unsigned)(i * 4 - (i * (i - 1)) / 2 + (j - i));
            float d12 = 0.5f * (dsrc + dtgt);
            float scale = 2.0f * ss * st;
            unsigned tq = (unsigned)fminf(fmaxf(th1 * (65535.0f / 3.14159265358979f) + 0.5f, 0.f), 65535.f);
            unsigned dq = (unsigned)fminf(fmaxf((d12 - 0.8f) * (65535.0f / 2.7f) + 0.5f, 0.f), 65535.f);
            unsigned sq = (unsigned)fminf(fmaxf(scale * (65535.0f / 2.0f) + 0.5f, 0.f), 65535.f);
            uint2 pl; pl.x = tq | (dq << 16); pl.y = sq | ((unsigned)(c1i & 127) << 16) | (pair << 23);
            int b = c1i >> 7;
            int slot = atomicAdd(&lcnt[b], 1);
            if (slot < SC_K) stg[b * SC_K + slot] = pl;
            else { int oi = atomicAdd(ovfc, 1); if (oi < OVF_CAP) ovf[oi] = make_uint4(pl.x, pl.y, (unsigned)c1i, 1u); }
        }
        if (++pend == SC_F || i0 + 1024 >= end)
            { pend = 0; flush_buckets(lcnt, stg, gcnt, payload, ovf, ovfc, nb, 1u); }
    }
}

// ---------------- per-item accumulate helpers: window + per-lane threshold ----------------
#define VTHR 1.5e-3f

__device__ __forceinline__ void proc_rad(uint2 pl, float* acc) {
    float d = 0.8f + (float)(pl.x & 0xffffu) * (4.4f / 65535.0f);
    float coef = 0.25f * (float)(pl.x >> 16) * (1.0f / 65535.0f);
    int bidx = (int)(pl.y & 63u) * 129 + (int)((pl.y >> 7) & 3u) * 32 + (int)((pl.y >> 9) & 1u);
    int c0 = (int)((d - 0.8f) * (1.0f / 0.275f)) - 1;
    c0 = max(0, min(12, c0));
    float dd = d - (0.8f + 0.275f * (float)c0);
    float* ap = acc + bidx + c0 * 2;
#pragma unroll
    for (int kk = 0; kk < 4; ++kk) {
        float delta = dd - 0.275f * (float)kk;
        float v = coef * __expf(-16.0f * delta * delta);
        if (v > VTHR) atomicAdd(&ap[kk * 2], v);
    }
}

__device__ __forceinline__ void proc_ang(uint2 pl, float* acc) {
    float th    = (float)(pl.x & 0xffffu) * (3.14159265358979f / 65535.0f);
    float d12   = 0.8f + (float)(pl.x >> 16) * (2.7f / 65535.0f);
    float scale = (float)(pl.y & 0xffffu) * (2.0f / 65535.0f);
    int rowb = (int)((pl.y >> 16) & 63u) * 161 + (int)((pl.y >> 23) & 15u) * 16;
    int z0 = (int)(th * (4.0f / 3.14159265358979f) - 0.5f);
    z0 = max(0, min(2, z0));
    float cz = (z0 == 0) ? 0.92387953251f : ((z0 == 1) ? 0.38268343236f : -0.38268343236f);
    float sz = (z0 == 0) ? 0.38268343236f : 0.92387953251f;
    float sth, cth;
    __sincosf(th, &sth, &cth);
    float cq = cth * cz + sth * sz;
    float sq = sth * cz - cth * sz;
    float xa = 0.5f + 0.5f * cq;
    float cq1 = 0.70710678119f * (cq + sq);
    float xb = 0.5f + 0.5f * cq1;
    float x2, x4, x8, x16, f1a, f1b;
    x2 = xa * xa; x4 = x2 * x2; x8 = x4 * x4; x16 = x8 * x8; f1a = x16 * x16;
    x2 = xb * xb; x4 = x2 * x2; x8 = x4 * x4; x16 = x8 * x8; f1b = x16 * x16;
    int ar = (int)((d12 - 0.8f) * (1.0f / 0.675f) + 0.5f);
    int a0 = max(0, min(1, ar - 1));
    float da = d12 - (0.8f + 0.675f * (float)a0);
    float* ap = acc + rowb + a0 * 4 + z0;
#pragma unroll
    for (int aa = 0; aa < 3; ++aa) {
        float delta = da - 0.675f * (float)aa;
        float f2 = __expf(-8.0f * delta * delta) * scale;
        float v0 = f2 * f1a;
        float v1 = f2 * f1b;
        if (v0 > VTHR) atomicAdd(&ap[aa * 4], v0);
        if (v1 > VTHR) atomicAdd(&ap[aa * 4 + 1], v1);
    }
}

// ================= accumulate device bodies (half-bin filter, g = 64-atom index) =================
__device__ __forceinline__ void accum_rad_dev(const uint2* __restrict__ payload,
                                              const int* __restrict__ gcnt,
                                              float* __restrict__ out, int n_atoms,
                                              int g, float* acc) {
    int bin = g >> 1, half = g & 1;
    for (int i = threadIdx.x; i < 64 * 129; i += 512) acc[i] = 0.f;
    __syncthreads();
    int len = min(gcnt[bin], CAP);
    const uint2* pp = payload + (size_t)bin * CAP;
    for (int r = threadIdx.x; r < len; r += 512) {
        uint2 pl = pp[r];
        if ((int)((pl.y >> 6) & 1u) == half) proc_rad(pl, acc);
    }
    __syncthreads();
    int a0 = g * 64;
    for (int i = threadIdx.x; i < 64 * 128; i += 512) {
        int la = i >> 7, cc = i & 127;
        int atom = a0 + la;
        if (atom < n_atoms) out[(size_t)atom * OUTC + 16 + cc] = acc[la * 129 + cc];
    }
}

__device__ __forceinline__ void accum_ang_dev(const uint2* __restrict__ payload,
                                              const int* __restrict__ gcnt,
                                              float* __restrict__ out, int n_atoms,
                                              int g, float* acc) {
    int bin = g >> 1, half = g & 1;
    for (int i = threadIdx.x; i < 64 * 161; i += 512) acc[i] = 0.f;
    __syncthreads();
    int len = min(gcnt[bin], CAP);
    const uint2* pp = payload + (size_t)bin * CAP;
    for (int r = threadIdx.x; r < len; r += 512) {
        uint2 pl = pp[r];
        if ((int)((pl.y >> 22) & 1u) == half) proc_ang(pl, acc);
    }
    __syncthreads();
    int a0 = g * 64;
    for (int i = threadIdx.x; i < 64 * 160; i += 512) {
        int la = i / 160, cc = i - la * 160;
        int atom = a0 + la;
        if (atom < n_atoms) out[(size_t)atom * OUTC + 144 + cc] = acc[la * 161 + cc];
    }
}

// ================= fused kernels (dual-payload path) =================
__global__ __launch_bounds__(512) void k_scatter_fused(
        const float* __restrict__ dist, const float* __restrict__ sw,
        const int* __restrict__ bond_order, const int* __restrict__ esrc,
        const int* __restrict__ edst, const int* __restrict__ species,
        int* __restrict__ gcntR, uint2* __restrict__ payR,
        const float* __restrict__ angles, const unsigned* __restrict__ erec,
        const int* __restrict__ central, const int* __restrict__ psrc,
        const int* __restrict__ pdst,
        int* __restrict__ gcntA, uint2* __restrict__ payA,
        uint4* __restrict__ ovf, int* __restrict__ ovfc,
        int e_rad, int n_pairs, int span, int nb, int gridR, int gridA) {
    __shared__ uint2 stg[NBK * SC_K];
    __shared__ int lcnt[NBK];
    int m = min(gridR, gridA), m2 = 2 * m;
    int bi = (int)blockIdx.x;
    bool ang; int bidx;
    if (bi < m2) { ang = bi & 1; bidx = bi >> 1; }
    else { ang = (gridA > gridR); bidx = m + (bi - m2); }
    if (ang)
        scatter_ang_dev(angles, erec, central, psrc, pdst, gcntA, payA,
                        ovf, ovfc, n_pairs, span, nb, bidx, stg, lcnt);
    else
        scatter_rad_dev(dist, sw, bond_order, esrc, edst, species, gcntR, payR,
                        ovf, ovfc, e_rad, span, nb, bidx, stg, lcnt);
}

__global__ __launch_bounds__(512) void k_accum_fused(const uint2* __restrict__ payR,
                                                     const int* __restrict__ gcntR,
                                                     const uint2* __restrict__ payA,
                                                     const int* __restrict__ gcntA,
                                                     float* __restrict__ out, int n_atoms) {
    __shared__ float acc[64 * 161];   // 41 KB frame shared by both types
    int g = blockIdx.x >> 1;
    if (blockIdx.x & 1) accum_ang_dev(payA, gcntA, out, n_atoms, g, acc);
    else                accum_rad_dev(payR, gcntR, out, n_atoms, g, acc);
}

// ---------------- overflow spill (rare; exact full window) ----------------
__global__ __launch_bounds__(256) void k_spill(const uint4* __restrict__ ovf,
                                               const int* __restrict__ ovfc,
                                               float* __restrict__ out) {
    int n = min(*ovfc, OVF_CAP);
    const float CZ[4] = {0.92387953251f, 0.38268343236f, -0.38268343236f, -0.92387953251f};
    const float SZ[4] = {0.38268343236f, 0.92387953251f, 0.92387953251f, 0.38268343236f};
    for (int idx = blockIdx.x * 256 + threadIdx.x; idx < n; idx += gridDim.x * 256) {
        uint4 e = ovf[idx];
        if (e.w == 0u) {   // radial
            float d = 0.8f + (float)(e.x & 0xffffu) * (4.4f / 65535.0f);
            float coef = 0.25f * (float)(e.x >> 16) * (1.0f / 65535.0f);
            int sp = (int)((e.y >> 7) & 3u), bb = (int)((e.y >> 9) & 1u);
            float* base = out + (size_t)e.z * OUTC + 16 + sp * 32 + bb;
            for (int k = 0; k < 16; ++k) {
                float delta = d - (0.8f + 0.275f * (float)k);
                float v = coef * __expf(-16.0f * delta * delta);
                if (v > 1e-6f) unsafeAtomicAdd(base + k * 2, v);
            }
        } else {           // angular
            float th    = (float)(e.x & 0xffffu) * (3.14159265358979f / 65535.0f);
            float d12   = 0.8f + (float)(e.x >> 16) * (2.7f / 65535.0f);
            float scale = (float)(e.y & 0xffffu) * (2.0f / 65535.0f);
            int pair = (int)((e.y >> 23) & 15u);
            float* base = out + (size_t)e.z * OUTC + 144 + pair * 16;
            float sth, cth;
            __sincosf(th, &sth, &cth);
            for (int zz = 0; zz < 4; ++zz) {
                float x = 0.5f + 0.5f * (cth * CZ[zz] + sth * SZ[zz]);
                float x2 = x * x, x4 = x2 * x2, x8 = x4 * x4, x16 = x8 * x8;
                float f1 = x16 * x16;
                for (int a = 0; a < 4; ++a) {
                    float da = d12 - (0.8f + 0.675f * (float)a);
                    float v = __expf(-8.0f * da * da) * scale * f1;
                    if (v > 1e-6f) unsafeAtomicAdd(base + a * 4 + zz, v);
                }
            }
        }
    }
}

// ================= fallback (round-1 atomic path) =================
__global__ __launch_bounds__(256) void k_init_fb(const float* __restrict__ ecfp,
                                                 float* __restrict__ out, int total4) {
    int i = blockIdx.x * 256 + threadIdx.x;
    if (i >= total4) return;
    int row = i / 76, c4 = i - row * 76;
    float4 v = make_float4(0.f, 0.f, 0.f, 0.f);
    if (c4 < 4) v = ((const float4*)ecfp)[row * 4 + c4];
    ((float4*)out)[i] = v;
}

__global__ __launch_bounds__(256) void k_radial_fb(const float* __restrict__ dist,
                                                   const float* __restrict__ sw,
                                                   const int* __restrict__ bond_order,
                                                   const int* __restrict__ esrc,
                                                   const int* __restrict__ edst,
                                                   const int* __restrict__ species,
                                                   float* __restrict__ out, int e_rad) {
    int e = blockIdx.x * 256 + threadIdx.x;
    if (e >= e_rad) return;
    float d = dist[e], s = sw[e];
    int bo = bond_order[e];
    int bb = (bo == 3 || bo == 5) ? 1 : 0;
    int z = species[edst[e]];
    int sp = (z == 6) ? 1 : (z == 7) ? 2 : (z == 8) ? 3 : 0;
    float* base = out + (size_t)esrc[e] * OUTC + 16 + sp * 32 + bb;
    float coef = 0.25f * s;
#pragma unroll
    for (int r = 0; r < 16; ++r) {
        float delta = d - (0.8f + 0.275f * (float)r);
        float v = coef * __expf(-16.0f * delta * delta);
        if (v > 6e-7f) unsafeAtomicAdd(base + r * 2, v);
    }
}

__global__ __launch_bounds__(256) void k_ang_fb(const float* __restrict__ angles,
                                                const float* __restrict__ angd,
                                                const float* __restrict__ angsw,
                                                const int* __restrict__ aedst,
                                                const int* __restrict__ species,
                                                const int* __restrict__ central,
                                                const int* __restrict__ psrc,
                                                const int* __restrict__ pdst,
                                                float* __restrict__ out, int n_pairs) {
    int p = blockIdx.x * 256 + threadIdx.x;
    if (p >= n_pairs) return;
    int is = psrc[p], it = pdst[p];
    float th = angles[p];
    float d12 = 0.5f * (angd[is] + angd[it]);
    float scale = 2.0f * angsw[is] * angsw[it];
    int zs = species[aedst[is]], zt = species[aedst[it]];
    int sps = (zs == 6) ? 1 : (zs == 7) ? 2 : (zs == 8) ? 3 : 0;
    int spt = (zt == 6) ? 1 : (zt == 7) ? 2 : (zt == 8) ? 3 : 0;
    int i = min(sps, spt), j = max(sps, spt);
    int pair = i * 4 - (i * (i - 1)) / 2 + (j - i);
    float sth, cth;
    __sincosf(th, &sth, &cth);
    const float CZ[4] = {0.92387953251f, 0.38268343236f, -0.38268343236f, -0.92387953251f};
    const float SZ[4] = {0.38268343236f, 0.92387953251f, 0.92387953251f, 0.38268343236f};
    float f1[4];
#pragma unroll
    for (int zz = 0; zz < 4; ++zz) {
        float x = 0.5f + 0.5f * (cth * CZ[zz] + sth * SZ[zz]);
        float x2 = x * x, x4 = x2 * x2, x8 = x4 * x4, x16 = x8 * x8;
        f1[zz] = x16 * x16;
    }
    float* base = out + (size_t)central[p] * OUTC + 144 + pair * 16;
#pragma unroll
    for (int a = 0; a < 4; ++a) {
        float da = d12 - (0.8f + 0.675f * (float)a);
        float f2 = __expf(-8.0f * da * da) * scale;
#pragma unroll
        for (int zz = 0; zz < 4; ++zz) {
            float v = f2 * f1[zz];
            if (v > 6e-7f) unsafeAtomicAdd(base + a * 4 + zz, v);
        }
    }
}

extern "C" void kernel_launch(void* const* d_in, const int* in_sizes, int n_in,
                              void* d_out, int out_size, void* d_ws, size_t ws_size,
                              hipStream_t stream) {
    const float* ecfp      = (const float*)d_in[0];
    const float* distances = (const float*)d_in[1];
    const float* sw        = (const float*)d_in[2];
    const float* angles    = (const float*)d_in[3];
    const float* angd      = (const float*)d_in[4];
    const float* angsw     = (const float*)d_in[5];
    const int*   species   = (const int*)d_in[6];
    const int*   bond_ord  = (const int*)d_in[7];
    const int*   edge_src  = (const int*)d_in[8];
    const int*   edge_dst  = (const int*)d_in[9];
    const int*   aedst     = (const int*)d_in[10];
    const int*   central   = (const int*)d_in[11];
    const int*   angle_src = (const int*)d_in[12];
    const int*   angle_dst = (const int*)d_in[13];
    float* out = (float*)d_out;

    const int e_rad   = in_sizes[1];
    const int n_pairs = in_sizes[3];
    const int e_ang   = in_sizes[4];
    const int n_atoms = in_sizes[6];

    const int NB  = (n_atoms + 127) / 128;   // 128-atom scatter bins
    const int G64 = (n_atoms + 63) / 64;     // 64-atom accum groups

    size_t pay_bytes  = (size_t)NB * CAP * 8;
    size_t erec_bytes = ((size_t)e_ang * 4 + 15) & ~(size_t)15;
    size_t ovf_bytes  = (size_t)OVF_CAP * 16;
    size_t meta_bytes = (size_t)(2 * NB + 1) * 4;
    size_t need2 = 2 * pay_bytes + erec_bytes + ovf_bytes + meta_bytes;

    bool cap_ok = (NB <= NBK) &&
                  (e_rad  <= (size_t)NB * (CAP - 512)) &&
                  (n_pairs <= (size_t)NB * (CAP - 512));

    const int span = SC_F * 2 * 1024;   // 8 ILP-2 iterations, 2 flushes per block
    int gridR = (e_rad + span - 1) / span;
    int gridA = (n_pairs + span - 1) / span;
    int total4 = n_atoms * 4;
    int nz = 2 * NB + 1;
    int prepN = max(e_ang, max(total4, nz));

    if (ws_size >= need2 && cap_ok) {
        uint2*    payR = (uint2*)d_ws;
        uint2*    payA = (uint2*)((char*)d_ws + pay_bytes);
        unsigned* erec = (unsigned*)((char*)d_ws + 2 * pay_bytes);
        uint4*    ovf  = (uint4*)((char*)d_ws + 2 * pay_bytes + erec_bytes);
        int*      gcntR = (int*)((char*)ovf + ovf_bytes);
        int*      gcntA = gcntR + NB;
        int*      ovfc  = gcntA + NB;

        k_prep<<<(prepN + 255) / 256, 256, 0, stream>>>(angd, angsw, aedst, species,
                                                        erec, e_ang, ecfp, out, total4,
                                                        gcntR, nz);
        k_scatter_fused<<<gridR + gridA, 512, 0, stream>>>(
            distances, sw, bond_ord, edge_src, edge_dst, species, gcntR, payR,
            angles, erec, central, angle_src, angle_dst, gcntA, payA,
            ovf, ovfc, e_rad, n_pairs, span, NB, gridR, gridA);
        k_accum_fused<<<2 * G64, 512, 0, stream>>>(payR, gcntR, payA, gcntA, out, n_atoms);
        k_spill<<<16, 256, 0, stream>>>(ovf, ovfc, out);
    } else {
        int t4 = n_atoms * (OUTC / 4);
        k_init_fb<<<(t4 + 255) / 256, 256, 0, stream>>>(ecfp, out, t4);
        k_radial_fb<<<(e_rad + 255) / 256, 256, 0, stream>>>(distances, sw, bond_ord,
                                                             edge_src, edge_dst, species,
                                                             out, e_rad);
        k_ang_fb<<<(n_pairs + 255) / 256, 256, 0, stream>>>(angles, angd, angsw, aedst,
                                                            species, central, angle_src,
                                                            angle_dst, out, n_pairs);
    }
}